// Round 12
// baseline (777.276 us; speedup 1.0000x reference)
//
#include <hip/hip_runtime.h>
#include <float.h>

#define B_ 16
#define N_ 2048
#define KNN 20

typedef unsigned short u16;
typedef __attribute__((ext_vector_type(8))) short bf16x8;
typedef __attribute__((ext_vector_type(4))) float f32x4;

typedef const __attribute__((address_space(1))) unsigned gas_t;
typedef __attribute__((address_space(3))) unsigned las_t;

__device__ inline u16 bfhi(float v) {
    union { float f; unsigned u; } x; x.f = v;
    unsigned r = x.u + 0x7FFFu + ((x.u >> 16) & 1u);
    return (u16)(r >> 16);
}
__device__ inline u16 bflo(float v, u16 h) {
    union { unsigned u; float f; } y; y.u = ((unsigned)h) << 16;
    return bfhi(v - y.f);
}
__device__ inline unsigned fkey(float v) {
    union { float f; unsigned u; } x;
    x.f = fmaxf(v, 0.f);
    return x.u & 0x7FFFFFFFu;
}
__device__ inline unsigned umin_(unsigned a, unsigned b) { return a < b ? a : b; }

// ---------------- bitonic sort across 64 lanes (ascending by key) ----------------
template <bool P>
__device__ inline void bitonic64(unsigned& key, unsigned& pay, int lane) {
#pragma unroll
    for (int k = 2; k <= 64; k <<= 1) {
#pragma unroll
        for (int j = k >> 1; j > 0; j >>= 1) {
            unsigned ok = __shfl_xor(key, j);
            unsigned op = P ? __shfl_xor(pay, j) : 0u;
            bool up = ((lane & k) == 0);
            bool lower = ((lane & j) == 0);
            bool takeOther = (up == lower) ? (ok < key) : (ok > key);
            if (takeOther) { key = ok; if (P) pay = op; }
        }
    }
}

// ---------------- exact top-20-smallest via threshold filter ----------------
__device__ inline void select20(const unsigned* kr, int lane,
                                unsigned* klist, unsigned* ilist,
                                int* __restrict__ outIdx) {
    unsigned lm = kr[0];
#pragma unroll
    for (int i = 1; i < 32; ++i) lm = umin_(lm, kr[i]);
    unsigned dummy = 0, sk = lm;
    bitonic64<false>(sk, dummy, lane);
    unsigned S = __shfl(sk, 19);
    unsigned c = 0;
#pragma unroll
    for (int i = 0; i < 32; ++i) c += (kr[i] <= S) ? 1u : 0u;
    unsigned incl = c;
#pragma unroll
    for (int d = 1; d < 64; d <<= 1) {
        unsigned t = __shfl_up(incl, d);
        if (lane >= d) incl += t;
    }
    unsigned stot = __shfl(incl, 63);
    unsigned pos = incl - c;
    klist[lane] = 0xFFFFFFFFu;
    __syncthreads();
#pragma unroll
    for (int i = 0; i < 32; ++i) {
        if (kr[i] <= S) {
            if (pos < 64u) {
                klist[pos] = kr[i];
                ilist[pos] = ((unsigned)(i >> 2) << 8) + (unsigned)lane * 4u + (unsigned)(i & 3);
            }
            ++pos;
        }
    }
    __syncthreads();
    if (stot <= 64u) {
        unsigned key = klist[lane], pay = ilist[lane];
        bitonic64<true>(key, pay, lane);
        if (lane < KNN) outIdx[lane] = (int)pay;
    } else {
        unsigned taken = 0;
        for (int it = 0; it < KNN; ++it) {
            unsigned bk = 0xFFFFFFFFu; int bi = 0;
#pragma unroll
            for (int i = 0; i < 32; ++i) {
                bool better = (((taken >> i) & 1u) == 0u) && (kr[i] < bk);
                if (better) { bk = kr[i]; bi = i; }
            }
            unsigned bl = (unsigned)lane;
#pragma unroll
            for (int off = 32; off > 0; off >>= 1) {
                unsigned ok = __shfl_down(bk, off);
                unsigned ol = __shfl_down(bl, off);
                int oi = __shfl_down(bi, off);
                if (ok < bk) { bk = ok; bl = ol; bi = oi; }
            }
            bl = __shfl(bl, 0); bi = __shfl(bi, 0);
            if (lane == (int)bl) taken |= (1u << bi);
            if (lane == 0) outIdx[it] = (int)(((unsigned)(bi >> 2) << 8) + bl * 4u + (unsigned)(bi & 3));
        }
    }
}

// select for convs 2-4: reads precomputed uint keys
__launch_bounds__(256)
__global__ void select_kernel(const unsigned* __restrict__ dist, int* __restrict__ idx_out) {
    __shared__ unsigned kl[4][64], il[4][64];
    int tid = threadIdx.x, w = tid >> 6, lane = tid & 63;
    size_t q = (size_t)blockIdx.x * 4 + w;
    const unsigned* src = dist + q * N_;
    unsigned kr[32];
#pragma unroll
    for (int j = 0; j < 8; ++j) {
        uint4 v = *(const uint4*)&src[j * 256 + lane * 4];
        kr[j * 4 + 0] = v.x;
        kr[j * 4 + 1] = v.y;
        kr[j * 4 + 2] = v.z;
        kr[j * 4 + 3] = v.w;
    }
    select20(kr, lane, kl[w], il[w], idx_out + q * KNN);
}

// select for conv1: distances straight from 3-D coords; 16 queries per block
__launch_bounds__(256)
__global__ void select3_kernel(const float* __restrict__ x, int* __restrict__ idx_out) {
    __shared__ __align__(16) float cx[N_], cy[N_], cz[N_];
    __shared__ unsigned kl[4][64], il[4][64];
    int tid = threadIdx.x, blk = blockIdx.x;
    int b = blk >> 7, n0 = (blk & 127) * 16;
    for (int i = tid; i < N_; i += 256) {
        const float* p = x + (size_t)(b * N_ + i) * 3;
        cx[i] = p[0]; cy[i] = p[1]; cz[i] = p[2];
    }
    __syncthreads();
    int w = tid >> 6, lane = tid & 63;
    for (int r = 0; r < 4; ++r) {
        int q = n0 + r * 4 + w;
        float qx = cx[q], qy = cy[q], qz = cz[q];
        unsigned kr[32];
#pragma unroll
        for (int j = 0; j < 8; ++j) {
            float4 vx = *(const float4*)&cx[j * 256 + lane * 4];
            float4 vy = *(const float4*)&cy[j * 256 + lane * 4];
            float4 vz = *(const float4*)&cz[j * 256 + lane * 4];
            float dx, dy, dz;
            dx = qx - vx.x; dy = qy - vy.x; dz = qz - vz.x;
            kr[j * 4 + 0] = fkey(fmaf(dx, dx, fmaf(dy, dy, dz * dz)));
            dx = qx - vx.y; dy = qy - vy.y; dz = qz - vz.y;
            kr[j * 4 + 1] = fkey(fmaf(dx, dx, fmaf(dy, dy, dz * dz)));
            dx = qx - vx.z; dy = qy - vy.z; dz = qz - vz.z;
            kr[j * 4 + 2] = fkey(fmaf(dx, dx, fmaf(dy, dy, dz * dz)));
            dx = qx - vx.w; dy = qy - vy.w; dz = qz - vz.w;
            kr[j * 4 + 3] = fkey(fmaf(dx, dx, fmaf(dy, dy, dz * dz)));
        }
        select20(kr, lane, kl[w], il[w], idx_out + ((size_t)(b * N_ + q)) * KNN);
    }
}

// ---------------- weight prep ----------------
__global__ void wt_kernel(const float* __restrict__ w, const float* __restrict__ b,
                          float* __restrict__ wt, float* __restrict__ bt,
                          int C, int Cout) {
    int N2 = 2 * Cout;
    int t = blockIdx.x * 256 + threadIdx.x;
    if (t < C * N2) {
        int c = t / N2, d = t % N2;
        float v;
        if (d < Cout) v = w[c * Cout + d];
        else          v = w[(C + c) * Cout + (d - Cout)] - w[c * Cout + (d - Cout)];
        wt[t] = v;
    }
    if (t < N2) bt[t] = (t < Cout) ? 0.f : b[t - Cout];
}

__global__ void prep_edge_B(const float* __restrict__ w, const float* __restrict__ b,
                            u16* __restrict__ Bth, u16* __restrict__ Btl,
                            float* __restrict__ bt, int C, int Cout) {
    int N2 = 2 * Cout;
    int t = blockIdx.x * 256 + threadIdx.x;
    if (t < N2 * C) {
        int d = t / C, c = t % C;
        float v = (d < Cout) ? w[c * Cout + d]
                             : (w[(C + c) * Cout + (d - Cout)] - w[c * Cout + (d - Cout)]);
        u16 h = bfhi(v);
        Bth[t] = h; Btl[t] = bflo(v, h);
    }
    if (t < N2) bt[t] = (t < Cout) ? 0.f : b[t - Cout];
}

__global__ void prep_w5_kernel(const float* __restrict__ w5,
                               u16* __restrict__ Bth, u16* __restrict__ Btl) {
    int t = blockIdx.x * 256 + threadIdx.x;   // 1024*512
    int n = t / 512, k = t % 512;
    float v = w5[(size_t)k * 1024 + n];
    u16 h = bfhi(v);
    Bth[t] = h; Btl[t] = bflo(v, h);
}

// ---------------- split-bf16 MFMA GEMM, 128x128 tile, 4 waves (2x2) ----------------
// Staging: global_load_lds width=16, linear LDS [128][64] u16, XOR-swizzled granule.
// EPI 0/1: bijective XCD-chunked mapping — f%8 = XCD chunk, N-tiles innermost,
// so the 8 blocks sharing an A-panel run consecutively on ONE XCD (L2-resident).
// EPI=2 writes fkey(dist) as uint keys.
template <int EPI>
__launch_bounds__(256, 2)
__global__ void mfma_gemm(const u16* __restrict__ Ah, const u16* __restrict__ Al,
                          long long aZ, int lda,
                          const u16* __restrict__ Bh, const u16* __restrict__ Bl,
                          long long bZ, int ldb,
                          const float* __restrict__ ep, long long epZ,
                          float* __restrict__ out, long long outZ, int ldo,
                          int K) {
    __shared__ __align__(16) char smem[73728];
    u16* AsH = (u16*)(smem);
    u16* AsL = (u16*)(smem + 16384);
    u16* BsH = (u16*)(smem + 32768);
    u16* BsL = (u16*)(smem + 49152);
    unsigned (*LT)[136] = (unsigned(*)[136])(smem);   // alias, used post-loop (EPI=2)
    __shared__ float red[2][128];
    int tid = threadIdx.x;
    int m0, n0, mt = 0;
    if (EPI == 2) {
        int t = blockIdx.x, rem = 16, bi = 0;
        while (t >= rem) { t -= rem; ++bi; --rem; }
        m0 = bi * 128; n0 = (bi + t) * 128;
    } else {
        int MT = gridDim.x, NT = gridDim.y;
        int f = blockIdx.x + blockIdx.y * MT;
        int xcd = f & 7, s = f >> 3;
        int sm = s / NT;
        int nt = s - sm * NT;
        mt = xcd * (MT >> 3) + sm;
        m0 = mt * 128; n0 = nt * 128;
    }
    int z = blockIdx.z;
    const u16* ah = Ah + (size_t)z * aZ;
    const u16* al = Al + (size_t)z * aZ;
    const u16* bh = Bh + (size_t)z * bZ;
    const u16* bl = Bl + (size_t)z * bZ;
    const float* epz = ep + (size_t)z * epZ;
    float* op = out + (size_t)z * outZ;

    int wid = tid >> 6, lane = tid & 63;
    int wm = wid >> 1, wn = wid & 1;
    int l15 = lane & 15, l4 = lane >> 4;
    int lrow8 = lane >> 3;
    int lg = lane & 7;

    f32x4 acc[4][4];
#pragma unroll
    for (int i = 0; i < 4; ++i)
#pragma unroll
        for (int j = 0; j < 4; ++j) acc[i][j] = (f32x4){0.f, 0.f, 0.f, 0.f};

    for (int k0 = 0; k0 < K; k0 += 64) {
        if (k0) __syncthreads();
#pragma unroll
        for (int ch = 0; ch < 4; ++ch) {
            int row = wid * 32 + ch * 8 + lrow8;
            int gsrc = lg ^ (row & 7);
            unsigned ldsoff = (unsigned)(wid * 32 + ch * 8) * 64;
            size_t ga = (size_t)(m0 + row) * lda + k0 + gsrc * 8;
            size_t gb = (size_t)(n0 + row) * ldb + k0 + gsrc * 8;
            __builtin_amdgcn_global_load_lds((gas_t*)(ah + ga), (las_t*)(AsH + ldsoff), 16, 0, 0);
            __builtin_amdgcn_global_load_lds((gas_t*)(al + ga), (las_t*)(AsL + ldsoff), 16, 0, 0);
            __builtin_amdgcn_global_load_lds((gas_t*)(bh + gb), (las_t*)(BsH + ldsoff), 16, 0, 0);
            __builtin_amdgcn_global_load_lds((gas_t*)(bl + gb), (las_t*)(BsL + ldsoff), 16, 0, 0);
        }
        __syncthreads();
#pragma unroll
        for (int kk = 0; kk < 2; ++kk) {
            int ko_g = kk * 4 + l4;
            bf16x8 aH[4], aL[4], bH[4], bL[4];
#pragma unroll
            for (int i = 0; i < 4; ++i) {
                int ra = wm * 64 + i * 16 + l15;
                int oa = ra * 64 + ((ko_g ^ (ra & 7)) << 3);
                aH[i] = *(const bf16x8*)&AsH[oa];
                aL[i] = *(const bf16x8*)&AsL[oa];
                int rb = wn * 64 + i * 16 + l15;
                int ob = rb * 64 + ((ko_g ^ (rb & 7)) << 3);
                bH[i] = *(const bf16x8*)&BsH[ob];
                bL[i] = *(const bf16x8*)&BsL[ob];
            }
#pragma unroll
            for (int i = 0; i < 4; ++i)
#pragma unroll
                for (int j = 0; j < 4; ++j) {
                    acc[i][j] = __builtin_amdgcn_mfma_f32_16x16x32_bf16(aH[i], bH[j], acc[i][j], 0, 0, 0);
                    acc[i][j] = __builtin_amdgcn_mfma_f32_16x16x32_bf16(aH[i], bL[j], acc[i][j], 0, 0, 0);
                    acc[i][j] = __builtin_amdgcn_mfma_f32_16x16x32_bf16(aL[i], bH[j], acc[i][j], 0, 0, 0);
                }
        }
    }

    if (EPI == 0) {
#pragma unroll
        for (int i = 0; i < 4; ++i)
#pragma unroll
            for (int r = 0; r < 4; ++r) {
                int grow = m0 + wm * 64 + i * 16 + l4 * 4 + r;
#pragma unroll
                for (int j = 0; j < 4; ++j) {
                    int col = n0 + wn * 64 + j * 16 + l15;
                    op[(size_t)grow * ldo + col] = acc[i][j][r] + epz[col];
                }
            }
    } else if (EPI == 1) {
        float pm[4];
#pragma unroll
        for (int j = 0; j < 4; ++j) {
            float v = -FLT_MAX;
#pragma unroll
            for (int i = 0; i < 4; ++i)
#pragma unroll
                for (int r = 0; r < 4; ++r) v = fmaxf(v, acc[i][j][r]);
            v = fmaxf(v, __shfl_xor(v, 16));
            v = fmaxf(v, __shfl_xor(v, 32));
            pm[j] = v;
        }
        if (l4 == 0) {
#pragma unroll
            for (int j = 0; j < 4; ++j) red[wm][wn * 64 + j * 16 + l15] = pm[j];
        }
        __syncthreads();
        if (tid < 128) {
            float v = fmaxf(red[0][tid], red[1][tid]) + epz[n0 + tid];
            v = (v > 0.f) ? v : 0.2f * v;
            op[(size_t)mt * ldo + n0 + tid] = v;
        }
    } else {
        unsigned* opu = (unsigned*)op;
#pragma unroll
        for (int i = 0; i < 4; ++i)
#pragma unroll
            for (int r = 0; r < 4; ++r) {
                int grow = m0 + wm * 64 + i * 16 + l4 * 4 + r;
                float sm = epz[grow];
#pragma unroll
                for (int j = 0; j < 4; ++j) {
                    int col = n0 + wn * 64 + j * 16 + l15;
                    opu[(size_t)grow * ldo + col] = fkey(sm + epz[col] - 2.f * acc[i][j][r]);
                }
            }
        if (m0 != n0) {
            __syncthreads();
#pragma unroll
            for (int i = 0; i < 4; ++i)
#pragma unroll
                for (int j = 0; j < 4; ++j) {
                    int colL  = wn * 64 + j * 16 + l15;
                    int growL = wm * 64 + i * 16 + l4 * 4;
                    uint4 v;
                    v.x = fkey(epz[m0 + growL + 0] + epz[n0 + colL] - 2.f * acc[i][j][0]);
                    v.y = fkey(epz[m0 + growL + 1] + epz[n0 + colL] - 2.f * acc[i][j][1]);
                    v.z = fkey(epz[m0 + growL + 2] + epz[n0 + colL] - 2.f * acc[i][j][2]);
                    v.w = fkey(epz[m0 + growL + 3] + epz[n0 + colL] - 2.f * acc[i][j][3]);
                    *(uint4*)&LT[colL][growL] = v;
                }
            __syncthreads();
            for (int rr0 = 0; rr0 < 128; rr0 += 8) {
                int rr = rr0 + (tid >> 5), cc = (tid & 31) * 4;
                uint4 v = *(const uint4*)&LT[rr][cc];
                *(uint4*)&opu[(size_t)(n0 + rr) * ldo + m0 + cc] = v;
            }
        }
    }
}

// ---------------- conv1 direct GEMM (K=3) ----------------
__global__ void conv1_kernel(const float* __restrict__ x, const float* __restrict__ wt,
                             const float* __restrict__ bt, float* __restrict__ ut) {
    __shared__ float sw[3][128], sb[128];
    int tid = threadIdx.x;
    if (tid < 128) { sw[0][tid] = wt[tid]; sw[1][tid] = wt[128 + tid]; }
    else { int d = tid - 128; sw[2][d] = wt[256 + d]; sb[d] = bt[d]; }
    __syncthreads();
    int t = blockIdx.x * 256 + tid;
    int m = t >> 7, d = t & 127;
    const float* xm = x + (size_t)m * 3;
    float v = sb[d];
    v = fmaf(xm[0], sw[0][d], v);
    v = fmaf(xm[1], sw[1][d], v);
    v = fmaf(xm[2], sw[2][d], v);
    ut[(size_t)m * 128 + d] = v;
}

// ---------------- gather + leaky + max over k + fused next-conv sqnorm ----------------
template <int COUT>
__global__ void gather_max_kernel(const float* __restrict__ ut,
                                  const int* __restrict__ idx,
                                  u16* __restrict__ cathi, u16* __restrict__ catlo,
                                  int coloff, float* __restrict__ sqn_out) {
    const int P = 256 / COUT;
    int tid = threadIdx.x;
    int p = tid / COUT, d = tid % COUT;
    int nb = gridDim.x;
    int i = blockIdx.x;
    int half = (i >= (nb >> 1)) ? 1 : 0;
    int ii = i - half * (nb >> 1);
    int b = half * 8 + (ii & 7);
    int within = ii >> 3;
    int pt_base = b * 2048 + within * P;
    int pt = pt_base + p;
    int n = pt & 2047;
    __shared__ int sidx[P][KNN];
    __shared__ float wpart[4];
    for (int q = tid; q < P * KNN; q += 256) {
        int pp = q / KNN, kk = q % KNN;
        sidx[pp][kk] = idx[(size_t)(pt_base + pp) * KNN + kk];
    }
    __syncthreads();
    const int N2 = 2 * COUT;
    const float* utb = ut + (size_t)b * N_ * N2;
    float tval = utb[(size_t)n * N2 + COUT + d];
    float acc = -FLT_MAX;
#pragma unroll
    for (int k = 0; k < KNN; k++) {
        int j = __builtin_amdgcn_readfirstlane(sidx[p][k]);
        const float* rp = utb + (size_t)j * N2;
        float s = rp[d] + tval;
        s = (s > 0.f) ? s : 0.2f * s;
        acc = fmaxf(acc, s);
    }
    u16 h = bfhi(acc);
    u16 l = bflo(acc, h);
    cathi[(size_t)pt * 512 + coloff + d] = h;
    catlo[(size_t)pt * 512 + coloff + d] = l;
    if (sqn_out) {
        union { unsigned u; float f; } va, vb;
        va.u = ((unsigned)h) << 16; vb.u = ((unsigned)l) << 16;
        float v = va.f + vb.f;
        float sq = v * v;
#pragma unroll
        for (int off = 1; off < 64; off <<= 1) sq += __shfl_xor(sq, off);
        int wid = tid >> 6, lane = tid & 63;
        if (lane == 0) wpart[wid] = sq;
        __syncthreads();
        const int WPP = COUT / 64;
        if (tid < P) {
            float s2 = 0.f;
#pragma unroll
            for (int ww = 0; ww < WPP; ++ww) s2 += wpart[tid * WPP + ww];
            sqn_out[pt_base + tid] = s2;
        }
    }
}

// ---------------- feat = max over 16 row-blocks of gpart ----------------
__global__ void featmax_kernel(const float* __restrict__ gpart, float* __restrict__ feat) {
    int t = blockIdx.x * 256 + threadIdx.x;   // 16*1024
    int b = t >> 10, d = t & 1023;
    float m = -FLT_MAX;
    for (int rb = 0; rb < 16; ++rb)
        m = fmaxf(m, gpart[(size_t)(b * 16 + rb) * 1024 + d]);
    feat[t] = m;
}

// ---------------- FC k-split: partials over 64-k chunks; W read exactly once ----------------
__global__ void fc_part_kernel(const float* __restrict__ in, const float* __restrict__ W,
                               float* __restrict__ part, int N) {
    __shared__ float sin_[16][64];
    __shared__ float red[3][16][64];
    int tid = threadIdx.x, lane = tid & 63, g = tid >> 6;
    int col = blockIdx.x * 64 + lane;
    int k0 = blockIdx.y * 64;
    for (int i = tid; i < 1024; i += 256)
        sin_[i >> 6][i & 63] = in[(i >> 6) * 1024 + k0 + (i & 63)];
    __syncthreads();
    float acc[16];
#pragma unroll
    for (int b = 0; b < 16; ++b) acc[b] = 0.f;
    int kk0 = g * 16;
#pragma unroll
    for (int k = kk0; k < kk0 + 16; ++k) {
        float wv = W[(size_t)(k0 + k) * N + col];
#pragma unroll
        for (int b = 0; b < 16; ++b) acc[b] = fmaf(sin_[b][k], wv, acc[b]);
    }
    if (g) {
#pragma unroll
        for (int b = 0; b < 16; ++b) red[g - 1][b][lane] = acc[b];
    }
    __syncthreads();
    if (g == 0) {
#pragma unroll
        for (int b = 0; b < 16; ++b) {
            float v = acc[b] + red[0][b][lane] + red[1][b][lane] + red[2][b][lane];
            part[((size_t)blockIdx.y * 16 + b) * N + col] = v;
        }
    }
}

__global__ void fc_reduce_kernel(const float* __restrict__ part, const float* __restrict__ bias,
                                 float* __restrict__ out, int N, int act) {
    int t = blockIdx.x * 256 + threadIdx.x;
    int b = t / N, col = t % N;
    float s = bias[col];
#pragma unroll
    for (int ks = 0; ks < 16; ++ks) s += part[((size_t)ks * 16 + b) * N + col];
    if (act) s = fmaxf(s, 0.f);
    out[(size_t)b * N + col] = s;
}

// ---------------- chamfer pass A ----------------
__launch_bounds__(256)
__global__ void chamferA_kernel(const float* __restrict__ coarse,
                                const float* __restrict__ pts,
                                float* __restrict__ pA) {
    __shared__ float spx[2048], spy[2048], spz[2048];
    __shared__ float red[4];
    int b = blockIdx.x, ch = blockIdx.y, tid = threadIdx.x;
    const float* pb = pts + (size_t)b * 6144;
    for (int i = tid; i < 2048; i += 256) {
        spx[i] = pb[i * 3]; spy[i] = pb[i * 3 + 1]; spz[i] = pb[i * 3 + 2];
    }
    __syncthreads();
    int q = ch * 32 + (tid >> 3);
    int oct = tid & 7;
    const float* cp = coarse + (size_t)b * 3072 + q * 3;
    float cx = cp[0], cy = cp[1], cz = cp[2];
    float mn0 = FLT_MAX, mn1 = FLT_MAX, mn2 = FLT_MAX, mn3 = FLT_MAX;
    int n0 = oct * 256;
    for (int n = n0; n < n0 + 256; n += 4) {
        float dx, dy, dz;
        dx = cx - spx[n];     dy = cy - spy[n];     dz = cz - spz[n];
        mn0 = fminf(mn0, fmaf(dx, dx, fmaf(dy, dy, dz * dz)));
        dx = cx - spx[n + 1]; dy = cy - spy[n + 1]; dz = cz - spz[n + 1];
        mn1 = fminf(mn1, fmaf(dx, dx, fmaf(dy, dy, dz * dz)));
        dx = cx - spx[n + 2]; dy = cy - spy[n + 2]; dz = cz - spz[n + 2];
        mn2 = fminf(mn2, fmaf(dx, dx, fmaf(dy, dy, dz * dz)));
        dx = cx - spx[n + 3]; dy = cy - spy[n + 3]; dz = cz - spz[n + 3];
        mn3 = fminf(mn3, fmaf(dx, dx, fmaf(dy, dy, dz * dz)));
    }
    float mn = fminf(fminf(mn0, mn1), fminf(mn2, mn3));
    mn = fminf(mn, __shfl_xor(mn, 1));
    mn = fminf(mn, __shfl_xor(mn, 2));
    mn = fminf(mn, __shfl_xor(mn, 4));
    float s = (oct == 0) ? mn : 0.f;
#pragma unroll
    for (int off = 32; off > 0; off >>= 1) s += __shfl_down(s, off);
    int w = tid >> 6, lane = tid & 63;
    if (lane == 0) red[w] = s;
    __syncthreads();
    if (tid == 0) pA[b * 32 + ch] = red[0] + red[1] + red[2] + red[3];
}

// ---------------- chamfer pass B ----------------
__launch_bounds__(256)
__global__ void chamferB_kernel(const float* __restrict__ coarse,
                                const float* __restrict__ pts,
                                float* __restrict__ pB) {
    __shared__ float scx[1024], scy[1024], scz[1024];
    __shared__ float red[4];
    int b = blockIdx.x, ch = blockIdx.y, tid = threadIdx.x;
    const float* cb = coarse + (size_t)b * 3072;
    for (int i = tid; i < 1024; i += 256) {
        scx[i] = cb[i * 3]; scy[i] = cb[i * 3 + 1]; scz[i] = cb[i * 3 + 2];
    }
    __syncthreads();
    int p = ch * 64 + (tid >> 2);
    int quad = tid & 3;
    const float* pp = pts + (size_t)b * 6144 + p * 3;
    float px = pp[0], py = pp[1], pz = pp[2];
    float mn0 = FLT_MAX, mn1 = FLT_MAX, mn2 = FLT_MAX, mn3 = FLT_MAX;
    int m0 = quad * 256;
    for (int m = m0; m < m0 + 256; m += 4) {
        float dx, dy, dz;
        dx = px - scx[m];     dy = py - scy[m];     dz = pz - scz[m];
        mn0 = fminf(mn0, fmaf(dx, dx, fmaf(dy, dy, dz * dz)));
        dx = px - scx[m + 1]; dy = py - scy[m + 1]; dz = pz - scz[m + 1];
        mn1 = fminf(mn1, fmaf(dx, dx, fmaf(dy, dy, dz * dz)));
        dx = px - scx[m + 2]; dy = py - scy[m + 2]; dz = pz - scz[m + 2];
        mn2 = fminf(mn2, fmaf(dx, dx, fmaf(dy, dy, dz * dz)));
        dx = px - scx[m + 3]; dy = py - scy[m + 3]; dz = pz - scz[m + 3];
        mn3 = fminf(mn3, fmaf(dx, dx, fmaf(dy, dy, dz * dz)));
    }
    float mn = fminf(fminf(mn0, mn1), fminf(mn2, mn3));
    mn = fminf(mn, __shfl_xor(mn, 1));
    mn = fminf(mn, __shfl_xor(mn, 2));
    float s = (quad == 0) ? mn : 0.f;
#pragma unroll
    for (int off = 32; off > 0; off >>= 1) s += __shfl_down(s, off);
    int w = tid >> 6, lane = tid & 63;
    if (lane == 0) red[w] = s;
    __syncthreads();
    if (tid == 0) pB[b * 32 + ch] = red[0] + red[1] + red[2] + red[3];
}

__global__ void loss_kernel(const float* __restrict__ pA, const float* __restrict__ pB,
                            float* __restrict__ out) {
    __shared__ float rA[4], rB[4];
    int tid = threadIdx.x;   // 256
    float a = pA[tid] + pA[tid + 256];
    float b = pB[tid] + pB[tid + 256];
#pragma unroll
    for (int off = 32; off > 0; off >>= 1) {
        a += __shfl_down(a, off);
        b += __shfl_down(b, off);
    }
    int w = tid >> 6, lane = tid & 63;
    if (lane == 0) { rA[w] = a; rB[w] = b; }
    __syncthreads();
    if (tid == 0)
        out[0] = (rA[0] + rA[1] + rA[2] + rA[3]) / (16.f * 1024.f)
               + (rB[0] + rB[1] + rB[2] + rB[3]) / (16.f * 2048.f);
}

extern "C" void kernel_launch(void* const* d_in, const int* in_sizes, int n_in,
                              void* d_out, int out_size, void* d_ws, size_t ws_size,
                              hipStream_t stream) {
    const float* corrupted = (const float*)d_in[0];
    const float* pts = (const float*)d_in[1];
    const float* w1 = (const float*)d_in[2];   const float* b1 = (const float*)d_in[3];
    const float* w2 = (const float*)d_in[4];   const float* b2 = (const float*)d_in[5];
    const float* w3 = (const float*)d_in[6];   const float* b3 = (const float*)d_in[7];
    const float* w4 = (const float*)d_in[8];   const float* b4 = (const float*)d_in[9];
    const float* w5 = (const float*)d_in[10];  const float* b5 = (const float*)d_in[11];
    const float* fw1 = (const float*)d_in[12]; const float* fb1 = (const float*)d_in[13];
    const float* fw2 = (const float*)d_in[14]; const float* fb2 = (const float*)d_in[15];
    const float* fw3 = (const float*)d_in[16]; const float* fb3 = (const float*)d_in[17];
    float* out = (float*)d_out;

    char* ws = (char*)d_ws;
    u16*   cathi  = (u16*)(ws);                   // [32768][512] bf16 hi   32 MB
    u16*   catlo  = (u16*)(ws + 33554432);        // [32768][512] bf16 lo   32 MB
    float* ut     = (float*)(ws + 67108864);      // [32768][<=512] f32     64 MB (aliased dist/fcpart)
    unsigned* dist = (unsigned*)ut;
    float* fcpart = ut;                           // [16][16][<=3072] f32
    int*   idx    = (int*)  (ws + 134217728);     // [32768][20]
    float* sqn    = (float*)(ws + 136839168);     // [32768]
    u16*   Bth    = (u16*)(ws + 136970240);       // [<=1024][<=512] bf16   1 MB
    u16*   Btl    = (u16*)(ws + 138018816);       // 1 MB
    float* bt     = (float*)(ws + 139067392);     // [<=1024]
    float* gpart  = (float*)(ws + 139071488);     // [256][1024]            1 MB
    float* feat   = (float*)(ws + 140120064);     // [16][1024]
    float* h1     = (float*)(ws + 140185600);
    float* h2     = (float*)(ws + 140251136);
    float* coarse = (float*)(ws + 140316672);     // [16][3072]
    float* pA     = (float*)(ws + 140513280);     // [512]
    float* pB     = (float*)(ws + 140515328);     // [512]
    float* wtf    = (float*)Bth;                  // conv1 fp32 wt alias

    // ---- conv1: C=3 (direct-coord knn, direct K=3 GEMM) ----
    select3_kernel<<<2048, 256, 0, stream>>>(corrupted, idx);
    wt_kernel<<<2, 256, 0, stream>>>(w1, b1, wtf, bt, 3, 64);
    conv1_kernel<<<16384, 256, 0, stream>>>(corrupted, wtf, bt, ut);
    gather_max_kernel<64><<<8192, 256, 0, stream>>>(ut, idx, cathi, catlo, 0, sqn);

    // ---- convs 2-4: symmetric MFMA gram + select + MFMA edge GEMM + gather(+sqnorm) ----
    auto conv = [&](int coloff, int C, int Cout, const float* w, const float* bias, int colout,
                    bool needNextSqn) {
        int N2 = 2 * Cout;
        prep_edge_B<<<(N2 * C + 255) / 256, 256, 0, stream>>>(w, bias, Bth, Btl, bt, C, Cout);
        for (int g = 0; g < 4; ++g) {
            size_t off = ((size_t)g * 4 * N_) * 512 + coloff;
            mfma_gemm<2><<<dim3(136, 1, 4), 256, 0, stream>>>(
                cathi + off, catlo + off, (long long)N_ * 512, 512,
                cathi + off, catlo + off, (long long)N_ * 512, 512,
                sqn + (size_t)g * 4 * N_, N_,
                (float*)dist, (long long)N_ * N_, N_, C);
            select_kernel<<<2048, 256, 0, stream>>>(dist, idx + (size_t)g * 4 * N_ * KNN);
        }
        mfma_gemm<0><<<dim3(256, N2 / 128, 1), 256, 0, stream>>>(
            cathi + coloff, catlo + coloff, 0, 512,
            Bth, Btl, 0, C,
            bt, 0,
            ut, 0, N2, C);
        float* sq = needNextSqn ? sqn : nullptr;
        if (Cout == 64)       gather_max_kernel<64><<<8192, 256, 0, stream>>>(ut, idx, cathi, catlo, colout, sq);
        else if (Cout == 128) gather_max_kernel<128><<<16384, 256, 0, stream>>>(ut, idx, cathi, catlo, colout, sq);
        else                  gather_max_kernel<256><<<32768, 256, 0, stream>>>(ut, idx, cathi, catlo, colout, sq);
    };
    conv(0, 64, 64, w2, b2, 64, true);
    conv(64, 64, 128, w3, b3, 128, true);
    conv(128, 128, 256, w4, b4, 256, false);

    // ---- w5 + leaky + max over N (fused epilogue) ----
    prep_w5_kernel<<<2048, 256, 0, stream>>>(w5, Bth, Btl);
    mfma_gemm<1><<<dim3(256, 8, 1), 256, 0, stream>>>(
        cathi, catlo, 0, 512,
        Bth, Btl, 0, 512,
        b5, 0,
        gpart, 0, 1024, 512);
    featmax_kernel<<<64, 256, 0, stream>>>(gpart, feat);

    // ---- FCs: k-split partials + reduce (deterministic) ----
    fc_part_kernel<<<dim3(16, 16), 256, 0, stream>>>(feat, fw1, fcpart, 1024);
    fc_reduce_kernel<<<64, 256, 0, stream>>>(fcpart, fb1, h1, 1024, 1);
    fc_part_kernel<<<dim3(16, 16), 256, 0, stream>>>(h1, fw2, fcpart, 1024);
    fc_reduce_kernel<<<64, 256, 0, stream>>>(fcpart, fb2, h2, 1024, 1);
    fc_part_kernel<<<dim3(48, 16), 256, 0, stream>>>(h2, fw3, fcpart, 3072);
    fc_reduce_kernel<<<192, 256, 0, stream>>>(fcpart, fb3, coarse, 3072, 0);

    chamferA_kernel<<<dim3(16, 32), 256, 0, stream>>>(coarse, pts, pA);
    chamferB_kernel<<<dim3(16, 32), 256, 0, stream>>>(coarse, pts, pB);
    loss_kernel<<<1, 256, 0, stream>>>(pA, pB, out);
}

// Round 13
// 720.218 us; speedup vs baseline: 1.0792x; 1.0792x over previous
//
#include <hip/hip_runtime.h>
#include <float.h>

#define B_ 16
#define N_ 2048
#define KNN 20

typedef unsigned short u16;
typedef __attribute__((ext_vector_type(8))) short bf16x8;
typedef __attribute__((ext_vector_type(4))) float f32x4;

typedef const __attribute__((address_space(1))) unsigned gas_t;
typedef __attribute__((address_space(3))) unsigned las_t;

__device__ inline u16 bfhi(float v) {
    union { float f; unsigned u; } x; x.f = v;
    unsigned r = x.u + 0x7FFFu + ((x.u >> 16) & 1u);
    return (u16)(r >> 16);
}
__device__ inline u16 bflo(float v, u16 h) {
    union { unsigned u; float f; } y; y.u = ((unsigned)h) << 16;
    return bfhi(v - y.f);
}
__device__ inline unsigned fkey(float v) {
    union { float f; unsigned u; } x;
    x.f = fmaxf(v, 0.f);
    return x.u & 0x7FFFFFFFu;
}
__device__ inline u16 fkey16(float v) { return (u16)(fkey(v) >> 15); }
__device__ inline unsigned umin_(unsigned a, unsigned b) { return a < b ? a : b; }

// payload (element index) encoding per keys-per-lane layout
template <int MODE>
__device__ inline unsigned payof(int i, int lane) {
    if (MODE == 0) return ((unsigned)(i >> 2) << 8) + (unsigned)lane * 4u + (unsigned)(i & 3);
    else           return ((unsigned)(i >> 3) << 9) + (unsigned)lane * 8u + (unsigned)(i & 7);
}

// ---------------- bitonic sort across 64 lanes (ascending by key) ----------------
template <bool P>
__device__ inline void bitonic64(unsigned& key, unsigned& pay, int lane) {
#pragma unroll
    for (int k = 2; k <= 64; k <<= 1) {
#pragma unroll
        for (int j = k >> 1; j > 0; j >>= 1) {
            unsigned ok = __shfl_xor(key, j);
            unsigned op = P ? __shfl_xor(pay, j) : 0u;
            bool up = ((lane & k) == 0);
            bool lower = ((lane & j) == 0);
            bool takeOther = (up == lower) ? (ok < key) : (ok > key);
            if (takeOther) { key = ok; if (P) pay = op; }
        }
    }
}

// ---------------- top-20-smallest via threshold filter ----------------
template <int MODE>
__device__ inline void select20(const unsigned* kr, int lane,
                                unsigned* klist, unsigned* ilist,
                                int* __restrict__ outIdx) {
    unsigned lm = kr[0];
#pragma unroll
    for (int i = 1; i < 32; ++i) lm = umin_(lm, kr[i]);
    unsigned dummy = 0, sk = lm;
    bitonic64<false>(sk, dummy, lane);
    unsigned S = __shfl(sk, 19);
    unsigned c = 0;
#pragma unroll
    for (int i = 0; i < 32; ++i) c += (kr[i] <= S) ? 1u : 0u;
    unsigned incl = c;
#pragma unroll
    for (int d = 1; d < 64; d <<= 1) {
        unsigned t = __shfl_up(incl, d);
        if (lane >= d) incl += t;
    }
    unsigned stot = __shfl(incl, 63);
    unsigned pos = incl - c;
    klist[lane] = 0xFFFFFFFFu;
    __syncthreads();
#pragma unroll
    for (int i = 0; i < 32; ++i) {
        if (kr[i] <= S) {
            if (pos < 64u) {
                klist[pos] = kr[i];
                ilist[pos] = payof<MODE>(i, lane);
            }
            ++pos;
        }
    }
    __syncthreads();
    if (stot <= 64u) {
        unsigned key = klist[lane], pay = ilist[lane];
        bitonic64<true>(key, pay, lane);
        if (lane < KNN) outIdx[lane] = (int)pay;
    } else {
        unsigned taken = 0;
        for (int it = 0; it < KNN; ++it) {
            unsigned bk = 0xFFFFFFFFu; int bi = 0;
#pragma unroll
            for (int i = 0; i < 32; ++i) {
                bool better = (((taken >> i) & 1u) == 0u) && (kr[i] < bk);
                if (better) { bk = kr[i]; bi = i; }
            }
            unsigned bl = (unsigned)lane;
#pragma unroll
            for (int off = 32; off > 0; off >>= 1) {
                unsigned ok = __shfl_down(bk, off);
                unsigned ol = __shfl_down(bl, off);
                int oi = __shfl_down(bi, off);
                if (ok < bk) { bk = ok; bl = ol; bi = oi; }
            }
            bl = __shfl(bl, 0); bi = __shfl(bi, 0);
            if (lane == (int)bl) taken |= (1u << bi);
            if (lane == 0) outIdx[it] = (int)payof<MODE>(bi, (int)bl);
        }
    }
}

// select for convs 2-4: reads precomputed u16 keys (8 keys/lane/chunk)
__launch_bounds__(256)
__global__ void select_kernel(const u16* __restrict__ dist, int* __restrict__ idx_out) {
    __shared__ unsigned kl[4][64], il[4][64];
    int tid = threadIdx.x, w = tid >> 6, lane = tid & 63;
    size_t q = (size_t)blockIdx.x * 4 + w;
    const u16* src = dist + q * N_;
    unsigned kr[32];
#pragma unroll
    for (int j = 0; j < 4; ++j) {
        uint4 v = *(const uint4*)&src[j * 512 + lane * 8];
        const unsigned* pw = (const unsigned*)&v;
#pragma unroll
        for (int e = 0; e < 4; ++e) {
            kr[j * 8 + 2 * e]     = pw[e] & 0xFFFFu;
            kr[j * 8 + 2 * e + 1] = pw[e] >> 16;
        }
    }
    select20<1>(kr, lane, kl[w], il[w], idx_out + q * KNN);
}

// select for conv1: distances straight from 3-D coords; 16 queries per block
__launch_bounds__(256)
__global__ void select3_kernel(const float* __restrict__ x, int* __restrict__ idx_out) {
    __shared__ __align__(16) float cx[N_], cy[N_], cz[N_];
    __shared__ unsigned kl[4][64], il[4][64];
    int tid = threadIdx.x, blk = blockIdx.x;
    int b = blk >> 7, n0 = (blk & 127) * 16;
    for (int i = tid; i < N_; i += 256) {
        const float* p = x + (size_t)(b * N_ + i) * 3;
        cx[i] = p[0]; cy[i] = p[1]; cz[i] = p[2];
    }
    __syncthreads();
    int w = tid >> 6, lane = tid & 63;
    for (int r = 0; r < 4; ++r) {
        int q = n0 + r * 4 + w;
        float qx = cx[q], qy = cy[q], qz = cz[q];
        unsigned kr[32];
#pragma unroll
        for (int j = 0; j < 8; ++j) {
            float4 vx = *(const float4*)&cx[j * 256 + lane * 4];
            float4 vy = *(const float4*)&cy[j * 256 + lane * 4];
            float4 vz = *(const float4*)&cz[j * 256 + lane * 4];
            float dx, dy, dz;
            dx = qx - vx.x; dy = qy - vy.x; dz = qz - vz.x;
            kr[j * 4 + 0] = fkey(fmaf(dx, dx, fmaf(dy, dy, dz * dz)));
            dx = qx - vx.y; dy = qy - vy.y; dz = qz - vz.y;
            kr[j * 4 + 1] = fkey(fmaf(dx, dx, fmaf(dy, dy, dz * dz)));
            dx = qx - vx.z; dy = qy - vy.z; dz = qz - vz.z;
            kr[j * 4 + 2] = fkey(fmaf(dx, dx, fmaf(dy, dy, dz * dz)));
            dx = qx - vx.w; dy = qy - vy.w; dz = qz - vz.w;
            kr[j * 4 + 3] = fkey(fmaf(dx, dx, fmaf(dy, dy, dz * dz)));
        }
        select20<0>(kr, lane, kl[w], il[w], idx_out + ((size_t)(b * N_ + q)) * KNN);
    }
}

// ---------------- weight prep ----------------
__global__ void wt_kernel(const float* __restrict__ w, const float* __restrict__ b,
                          float* __restrict__ wt, float* __restrict__ bt,
                          int C, int Cout) {
    int N2 = 2 * Cout;
    int t = blockIdx.x * 256 + threadIdx.x;
    if (t < C * N2) {
        int c = t / N2, d = t % N2;
        float v;
        if (d < Cout) v = w[c * Cout + d];
        else          v = w[(C + c) * Cout + (d - Cout)] - w[c * Cout + (d - Cout)];
        wt[t] = v;
    }
    if (t < N2) bt[t] = (t < Cout) ? 0.f : b[t - Cout];
}

__global__ void prep_edge_B(const float* __restrict__ w, const float* __restrict__ b,
                            u16* __restrict__ Bth, u16* __restrict__ Btl,
                            float* __restrict__ bt, int C, int Cout) {
    int N2 = 2 * Cout;
    int t = blockIdx.x * 256 + threadIdx.x;
    if (t < N2 * C) {
        int d = t / C, c = t % C;
        float v = (d < Cout) ? w[c * Cout + d]
                             : (w[(C + c) * Cout + (d - Cout)] - w[c * Cout + (d - Cout)]);
        u16 h = bfhi(v);
        Bth[t] = h; Btl[t] = bflo(v, h);
    }
    if (t < N2) bt[t] = (t < Cout) ? 0.f : b[t - Cout];
}

__global__ void prep_w5_kernel(const float* __restrict__ w5,
                               u16* __restrict__ Bth, u16* __restrict__ Btl) {
    int t = blockIdx.x * 256 + threadIdx.x;   // 1024*512
    int n = t / 512, k = t % 512;
    float v = w5[(size_t)k * 1024 + n];
    u16 h = bfhi(v);
    Bth[t] = h; Btl[t] = bflo(v, h);
}

// ---------------- split-bf16 MFMA GEMM, 128x128 tile, 4 waves (2x2) ----------------
// Staging: global_load_lds width=16, linear LDS, XOR-swizzled granule.
// EPI 0/1: bijective XCD-chunked block mapping. EPI=2: u16 dist keys.
template <int EPI>
__launch_bounds__(256, 2)
__global__ void mfma_gemm(const u16* __restrict__ Ah, const u16* __restrict__ Al,
                          long long aZ, int lda,
                          const u16* __restrict__ Bh, const u16* __restrict__ Bl,
                          long long bZ, int ldb,
                          const float* __restrict__ ep, long long epZ,
                          float* __restrict__ out, long long outZ, int ldo,
                          int K) {
    __shared__ __align__(16) char smem[73728];
    u16* AsH = (u16*)(smem);
    u16* AsL = (u16*)(smem + 16384);
    u16* BsH = (u16*)(smem + 32768);
    u16* BsL = (u16*)(smem + 49152);
    u16 (*LTs)[136] = (u16(*)[136])(smem);   // alias, used post-loop (EPI=2)
    __shared__ float red[2][128];
    int tid = threadIdx.x;
    int m0, n0, mt = 0;
    if (EPI == 2) {
        int t = blockIdx.x, rem = 16, bi = 0;
        while (t >= rem) { t -= rem; ++bi; --rem; }
        m0 = bi * 128; n0 = (bi + t) * 128;
    } else {
        int MT = gridDim.x, NT = gridDim.y;
        int f = blockIdx.x + blockIdx.y * MT;
        int xcd = f & 7, s = f >> 3;
        int sm = s / NT;
        int nt = s - sm * NT;
        mt = xcd * (MT >> 3) + sm;
        m0 = mt * 128; n0 = nt * 128;
    }
    int z = blockIdx.z;
    const u16* ah = Ah + (size_t)z * aZ;
    const u16* al = Al + (size_t)z * aZ;
    const u16* bh = Bh + (size_t)z * bZ;
    const u16* bl = Bl + (size_t)z * bZ;
    const float* epz = ep + (size_t)z * epZ;
    float* op = out + (size_t)z * outZ;

    int wid = tid >> 6, lane = tid & 63;
    int wm = wid >> 1, wn = wid & 1;
    int l15 = lane & 15, l4 = lane >> 4;
    int lrow8 = lane >> 3;
    int lg = lane & 7;

    f32x4 acc[4][4];
#pragma unroll
    for (int i = 0; i < 4; ++i)
#pragma unroll
        for (int j = 0; j < 4; ++j) acc[i][j] = (f32x4){0.f, 0.f, 0.f, 0.f};

    for (int k0 = 0; k0 < K; k0 += 64) {
        if (k0) __syncthreads();
#pragma unroll
        for (int ch = 0; ch < 4; ++ch) {
            int row = wid * 32 + ch * 8 + lrow8;
            int gsrc = lg ^ (row & 7);
            unsigned ldsoff = (unsigned)(wid * 32 + ch * 8) * 64;
            size_t ga = (size_t)(m0 + row) * lda + k0 + gsrc * 8;
            size_t gb = (size_t)(n0 + row) * ldb + k0 + gsrc * 8;
            __builtin_amdgcn_global_load_lds((gas_t*)(ah + ga), (las_t*)(AsH + ldsoff), 16, 0, 0);
            __builtin_amdgcn_global_load_lds((gas_t*)(al + ga), (las_t*)(AsL + ldsoff), 16, 0, 0);
            __builtin_amdgcn_global_load_lds((gas_t*)(bh + gb), (las_t*)(BsH + ldsoff), 16, 0, 0);
            __builtin_amdgcn_global_load_lds((gas_t*)(bl + gb), (las_t*)(BsL + ldsoff), 16, 0, 0);
        }
        __syncthreads();
#pragma unroll
        for (int kk = 0; kk < 2; ++kk) {
            int ko_g = kk * 4 + l4;
            bf16x8 aH[4], aL[4], bH[4], bL[4];
#pragma unroll
            for (int i = 0; i < 4; ++i) {
                int ra = wm * 64 + i * 16 + l15;
                int oa = ra * 64 + ((ko_g ^ (ra & 7)) << 3);
                aH[i] = *(const bf16x8*)&AsH[oa];
                aL[i] = *(const bf16x8*)&AsL[oa];
                int rb = wn * 64 + i * 16 + l15;
                int ob = rb * 64 + ((ko_g ^ (rb & 7)) << 3);
                bH[i] = *(const bf16x8*)&BsH[ob];
                bL[i] = *(const bf16x8*)&BsL[ob];
            }
#pragma unroll
            for (int i = 0; i < 4; ++i)
#pragma unroll
                for (int j = 0; j < 4; ++j) {
                    acc[i][j] = __builtin_amdgcn_mfma_f32_16x16x32_bf16(aH[i], bH[j], acc[i][j], 0, 0, 0);
                    acc[i][j] = __builtin_amdgcn_mfma_f32_16x16x32_bf16(aH[i], bL[j], acc[i][j], 0, 0, 0);
                    acc[i][j] = __builtin_amdgcn_mfma_f32_16x16x32_bf16(aL[i], bH[j], acc[i][j], 0, 0, 0);
                }
        }
    }

    if (EPI == 0) {
#pragma unroll
        for (int i = 0; i < 4; ++i)
#pragma unroll
            for (int r = 0; r < 4; ++r) {
                int grow = m0 + wm * 64 + i * 16 + l4 * 4 + r;
#pragma unroll
                for (int j = 0; j < 4; ++j) {
                    int col = n0 + wn * 64 + j * 16 + l15;
                    op[(size_t)grow * ldo + col] = acc[i][j][r] + epz[col];
                }
            }
    } else if (EPI == 1) {
        float pm[4];
#pragma unroll
        for (int j = 0; j < 4; ++j) {
            float v = -FLT_MAX;
#pragma unroll
            for (int i = 0; i < 4; ++i)
#pragma unroll
                for (int r = 0; r < 4; ++r) v = fmaxf(v, acc[i][j][r]);
            v = fmaxf(v, __shfl_xor(v, 16));
            v = fmaxf(v, __shfl_xor(v, 32));
            pm[j] = v;
        }
        if (l4 == 0) {
#pragma unroll
            for (int j = 0; j < 4; ++j) red[wm][wn * 64 + j * 16 + l15] = pm[j];
        }
        __syncthreads();
        if (tid < 128) {
            float v = fmaxf(red[0][tid], red[1][tid]) + epz[n0 + tid];
            v = (v > 0.f) ? v : 0.2f * v;
            op[(size_t)mt * ldo + n0 + tid] = v;
        }
    } else {
        u16* opu = (u16*)op;
#pragma unroll
        for (int i = 0; i < 4; ++i)
#pragma unroll
            for (int r = 0; r < 4; ++r) {
                int grow = m0 + wm * 64 + i * 16 + l4 * 4 + r;
                float sm = epz[grow];
#pragma unroll
                for (int j = 0; j < 4; ++j) {
                    int col = n0 + wn * 64 + j * 16 + l15;
                    opu[(size_t)grow * ldo + col] = fkey16(sm + epz[col] - 2.f * acc[i][j][r]);
                }
            }
        if (m0 != n0) {
            __syncthreads();   // staging LDS dead; safe to reuse as LTs
#pragma unroll
            for (int i = 0; i < 4; ++i)
#pragma unroll
                for (int j = 0; j < 4; ++j) {
                    int colL  = wn * 64 + j * 16 + l15;
                    int growL = wm * 64 + i * 16 + l4 * 4;
                    unsigned k0v = fkey16(epz[m0 + growL + 0] + epz[n0 + colL] - 2.f * acc[i][j][0]);
                    unsigned k1v = fkey16(epz[m0 + growL + 1] + epz[n0 + colL] - 2.f * acc[i][j][1]);
                    unsigned k2v = fkey16(epz[m0 + growL + 2] + epz[n0 + colL] - 2.f * acc[i][j][2]);
                    unsigned k3v = fkey16(epz[m0 + growL + 3] + epz[n0 + colL] - 2.f * acc[i][j][3]);
                    uint2 pk;
                    pk.x = k0v | (k1v << 16);
                    pk.y = k2v | (k3v << 16);
                    *(uint2*)&LTs[colL][growL] = pk;
                }
            __syncthreads();
            // mirror tile: rows n0..n0+127, cols m0..m0+127, coalesced (8B/lane)
            for (int rr0 = 0; rr0 < 128; rr0 += 8) {
                int rr = rr0 + (tid >> 5), cc = (tid & 31) * 4;
                uint2 v = *(const uint2*)&LTs[rr][cc];
                *(uint2*)&opu[(size_t)(n0 + rr) * ldo + m0 + cc] = v;
            }
        }
    }
}

// ---------------- conv1 direct GEMM (K=3) ----------------
__global__ void conv1_kernel(const float* __restrict__ x, const float* __restrict__ wt,
                             const float* __restrict__ bt, float* __restrict__ ut) {
    __shared__ float sw[3][128], sb[128];
    int tid = threadIdx.x;
    if (tid < 128) { sw[0][tid] = wt[tid]; sw[1][tid] = wt[128 + tid]; }
    else { int d = tid - 128; sw[2][d] = wt[256 + d]; sb[d] = bt[d]; }
    __syncthreads();
    int t = blockIdx.x * 256 + tid;
    int m = t >> 7, d = t & 127;
    const float* xm = x + (size_t)m * 3;
    float v = sb[d];
    v = fmaf(xm[0], sw[0][d], v);
    v = fmaf(xm[1], sw[1][d], v);
    v = fmaf(xm[2], sw[2][d], v);
    ut[(size_t)m * 128 + d] = v;
}

// ---------------- gather + leaky + max over k + fused next-conv sqnorm ----------------
template <int COUT>
__global__ void gather_max_kernel(const float* __restrict__ ut,
                                  const int* __restrict__ idx,
                                  u16* __restrict__ cathi, u16* __restrict__ catlo,
                                  int coloff, float* __restrict__ sqn_out) {
    const int P = 256 / COUT;
    int tid = threadIdx.x;
    int p = tid / COUT, d = tid % COUT;
    int nb = gridDim.x;
    int i = blockIdx.x;
    int half = (i >= (nb >> 1)) ? 1 : 0;
    int ii = i - half * (nb >> 1);
    int b = half * 8 + (ii & 7);
    int within = ii >> 3;
    int pt_base = b * 2048 + within * P;
    int pt = pt_base + p;
    int n = pt & 2047;
    __shared__ int sidx[P][KNN];
    __shared__ float wpart[4];
    for (int q = tid; q < P * KNN; q += 256) {
        int pp = q / KNN, kk = q % KNN;
        sidx[pp][kk] = idx[(size_t)(pt_base + pp) * KNN + kk];
    }
    __syncthreads();
    const int N2 = 2 * COUT;
    const float* utb = ut + (size_t)b * N_ * N2;
    float tval = utb[(size_t)n * N2 + COUT + d];
    float acc = -FLT_MAX;
#pragma unroll
    for (int k = 0; k < KNN; k++) {
        int j = __builtin_amdgcn_readfirstlane(sidx[p][k]);
        const float* rp = utb + (size_t)j * N2;
        float s = rp[d] + tval;
        s = (s > 0.f) ? s : 0.2f * s;
        acc = fmaxf(acc, s);
    }
    u16 h = bfhi(acc);
    u16 l = bflo(acc, h);
    cathi[(size_t)pt * 512 + coloff + d] = h;
    catlo[(size_t)pt * 512 + coloff + d] = l;
    if (sqn_out) {
        union { unsigned u; float f; } va, vb;
        va.u = ((unsigned)h) << 16; vb.u = ((unsigned)l) << 16;
        float v = va.f + vb.f;
        float sq = v * v;
#pragma unroll
        for (int off = 1; off < 64; off <<= 1) sq += __shfl_xor(sq, off);
        int wid = tid >> 6, lane = tid & 63;
        if (lane == 0) wpart[wid] = sq;
        __syncthreads();
        const int WPP = COUT / 64;
        if (tid < P) {
            float s2 = 0.f;
#pragma unroll
            for (int ww = 0; ww < WPP; ++ww) s2 += wpart[tid * WPP + ww];
            sqn_out[pt_base + tid] = s2;
        }
    }
}

// ---------------- feat = max over 16 row-blocks of gpart ----------------
__global__ void featmax_kernel(const float* __restrict__ gpart, float* __restrict__ feat) {
    int t = blockIdx.x * 256 + threadIdx.x;   // 16*1024
    int b = t >> 10, d = t & 1023;
    float m = -FLT_MAX;
    for (int rb = 0; rb < 16; ++rb)
        m = fmaxf(m, gpart[(size_t)(b * 16 + rb) * 1024 + d]);
    feat[t] = m;
}

// ---------------- FC k-split: partials over 64-k chunks; W read exactly once ----------------
__global__ void fc_part_kernel(const float* __restrict__ in, const float* __restrict__ W,
                               float* __restrict__ part, int N) {
    __shared__ float sin_[16][64];
    __shared__ float red[3][16][64];
    int tid = threadIdx.x, lane = tid & 63, g = tid >> 6;
    int col = blockIdx.x * 64 + lane;
    int k0 = blockIdx.y * 64;
    for (int i = tid; i < 1024; i += 256)
        sin_[i >> 6][i & 63] = in[(i >> 6) * 1024 + k0 + (i & 63)];
    __syncthreads();
    float acc[16];
#pragma unroll
    for (int b = 0; b < 16; ++b) acc[b] = 0.f;
    int kk0 = g * 16;
#pragma unroll
    for (int k = kk0; k < kk0 + 16; ++k) {
        float wv = W[(size_t)(k0 + k) * N + col];
#pragma unroll
        for (int b = 0; b < 16; ++b) acc[b] = fmaf(sin_[b][k], wv, acc[b]);
    }
    if (g) {
#pragma unroll
        for (int b = 0; b < 16; ++b) red[g - 1][b][lane] = acc[b];
    }
    __syncthreads();
    if (g == 0) {
#pragma unroll
        for (int b = 0; b < 16; ++b) {
            float v = acc[b] + red[0][b][lane] + red[1][b][lane] + red[2][b][lane];
            part[((size_t)blockIdx.y * 16 + b) * N + col] = v;
        }
    }
}

__global__ void fc_reduce_kernel(const float* __restrict__ part, const float* __restrict__ bias,
                                 float* __restrict__ out, int N, int act) {
    int t = blockIdx.x * 256 + threadIdx.x;
    int b = t / N, col = t % N;
    float s = bias[col];
#pragma unroll
    for (int ks = 0; ks < 16; ++ks) s += part[((size_t)ks * 16 + b) * N + col];
    if (act) s = fmaxf(s, 0.f);
    out[(size_t)b * N + col] = s;
}

// ---------------- chamfer pass A ----------------
__launch_bounds__(256)
__global__ void chamferA_kernel(const float* __restrict__ coarse,
                                const float* __restrict__ pts,
                                float* __restrict__ pA) {
    __shared__ float spx[2048], spy[2048], spz[2048];
    __shared__ float red[4];
    int b = blockIdx.x, ch = blockIdx.y, tid = threadIdx.x;
    const float* pb = pts + (size_t)b * 6144;
    for (int i = tid; i < 2048; i += 256) {
        spx[i] = pb[i * 3]; spy[i] = pb[i * 3 + 1]; spz[i] = pb[i * 3 + 2];
    }
    __syncthreads();
    int q = ch * 32 + (tid >> 3);
    int oct = tid & 7;
    const float* cp = coarse + (size_t)b * 3072 + q * 3;
    float cx = cp[0], cy = cp[1], cz = cp[2];
    float mn0 = FLT_MAX, mn1 = FLT_MAX, mn2 = FLT_MAX, mn3 = FLT_MAX;
    int n0 = oct * 256;
    for (int n = n0; n < n0 + 256; n += 4) {
        float dx, dy, dz;
        dx = cx - spx[n];     dy = cy - spy[n];     dz = cz - spz[n];
        mn0 = fminf(mn0, fmaf(dx, dx, fmaf(dy, dy, dz * dz)));
        dx = cx - spx[n + 1]; dy = cy - spy[n + 1]; dz = cz - spz[n + 1];
        mn1 = fminf(mn1, fmaf(dx, dx, fmaf(dy, dy, dz * dz)));
        dx = cx - spx[n + 2]; dy = cy - spy[n + 2]; dz = cz - spz[n + 2];
        mn2 = fminf(mn2, fmaf(dx, dx, fmaf(dy, dy, dz * dz)));
        dx = cx - spx[n + 3]; dy = cy - spy[n + 3]; dz = cz - spz[n + 3];
        mn3 = fminf(mn3, fmaf(dx, dx, fmaf(dy, dy, dz * dz)));
    }
    float mn = fminf(fminf(mn0, mn1), fminf(mn2, mn3));
    mn = fminf(mn, __shfl_xor(mn, 1));
    mn = fminf(mn, __shfl_xor(mn, 2));
    mn = fminf(mn, __shfl_xor(mn, 4));
    float s = (oct == 0) ? mn : 0.f;
#pragma unroll
    for (int off = 32; off > 0; off >>= 1) s += __shfl_down(s, off);
    int w = tid >> 6, lane = tid & 63;
    if (lane == 0) red[w] = s;
    __syncthreads();
    if (tid == 0) pA[b * 32 + ch] = red[0] + red[1] + red[2] + red[3];
}

// ---------------- chamfer pass B ----------------
__launch_bounds__(256)
__global__ void chamferB_kernel(const float* __restrict__ coarse,
                                const float* __restrict__ pts,
                                float* __restrict__ pB) {
    __shared__ float scx[1024], scy[1024], scz[1024];
    __shared__ float red[4];
    int b = blockIdx.x, ch = blockIdx.y, tid = threadIdx.x;
    const float* cb = coarse + (size_t)b * 3072;
    for (int i = tid; i < 1024; i += 256) {
        scx[i] = cb[i * 3]; scy[i] = cb[i * 3 + 1]; scz[i] = cb[i * 3 + 2];
    }
    __syncthreads();
    int p = ch * 64 + (tid >> 2);
    int quad = tid & 3;
    const float* pp = pts + (size_t)b * 6144 + p * 3;
    float px = pp[0], py = pp[1], pz = pp[2];
    float mn0 = FLT_MAX, mn1 = FLT_MAX, mn2 = FLT_MAX, mn3 = FLT_MAX;
    int m0 = quad * 256;
    for (int m = m0; m < m0 + 256; m += 4) {
        float dx, dy, dz;
        dx = px - scx[m];     dy = py - scy[m];     dz = pz - scz[m];
        mn0 = fminf(mn0, fmaf(dx, dx, fmaf(dy, dy, dz * dz)));
        dx = px - scx[m + 1]; dy = py - scy[m + 1]; dz = pz - scz[m + 1];
        mn1 = fminf(mn1, fmaf(dx, dx, fmaf(dy, dy, dz * dz)));
        dx = px - scx[m + 2]; dy = py - scy[m + 2]; dz = pz - scz[m + 2];
        mn2 = fminf(mn2, fmaf(dx, dx, fmaf(dy, dy, dz * dz)));
        dx = px - scx[m + 3]; dy = py - scy[m + 3]; dz = pz - scz[m + 3];
        mn3 = fminf(mn3, fmaf(dx, dx, fmaf(dy, dy, dz * dz)));
    }
    float mn = fminf(fminf(mn0, mn1), fminf(mn2, mn3));
    mn = fminf(mn, __shfl_xor(mn, 1));
    mn = fminf(mn, __shfl_xor(mn, 2));
    float s = (quad == 0) ? mn : 0.f;
#pragma unroll
    for (int off = 32; off > 0; off >>= 1) s += __shfl_down(s, off);
    int w = tid >> 6, lane = tid & 63;
    if (lane == 0) red[w] = s;
    __syncthreads();
    if (tid == 0) pB[b * 32 + ch] = red[0] + red[1] + red[2] + red[3];
}

__global__ void loss_kernel(const float* __restrict__ pA, const float* __restrict__ pB,
                            float* __restrict__ out) {
    __shared__ float rA[4], rB[4];
    int tid = threadIdx.x;   // 256
    float a = pA[tid] + pA[tid + 256];
    float b = pB[tid] + pB[tid + 256];
#pragma unroll
    for (int off = 32; off > 0; off >>= 1) {
        a += __shfl_down(a, off);
        b += __shfl_down(b, off);
    }
    int w = tid >> 6, lane = tid & 63;
    if (lane == 0) { rA[w] = a; rB[w] = b; }
    __syncthreads();
    if (tid == 0)
        out[0] = (rA[0] + rA[1] + rA[2] + rA[3]) / (16.f * 1024.f)
               + (rB[0] + rB[1] + rB[2] + rB[3]) / (16.f * 2048.f);
}

extern "C" void kernel_launch(void* const* d_in, const int* in_sizes, int n_in,
                              void* d_out, int out_size, void* d_ws, size_t ws_size,
                              hipStream_t stream) {
    const float* corrupted = (const float*)d_in[0];
    const float* pts = (const float*)d_in[1];
    const float* w1 = (const float*)d_in[2];   const float* b1 = (const float*)d_in[3];
    const float* w2 = (const float*)d_in[4];   const float* b2 = (const float*)d_in[5];
    const float* w3 = (const float*)d_in[6];   const float* b3 = (const float*)d_in[7];
    const float* w4 = (const float*)d_in[8];   const float* b4 = (const float*)d_in[9];
    const float* w5 = (const float*)d_in[10];  const float* b5 = (const float*)d_in[11];
    const float* fw1 = (const float*)d_in[12]; const float* fb1 = (const float*)d_in[13];
    const float* fw2 = (const float*)d_in[14]; const float* fb2 = (const float*)d_in[15];
    const float* fw3 = (const float*)d_in[16]; const float* fb3 = (const float*)d_in[17];
    float* out = (float*)d_out;

    char* ws = (char*)d_ws;
    u16*   cathi  = (u16*)(ws);                   // [32768][512] bf16 hi   32 MB
    u16*   catlo  = (u16*)(ws + 33554432);        // [32768][512] bf16 lo   32 MB
    float* ut     = (float*)(ws + 67108864);      // [32768][<=512] f32     64 MB (aliased dist/fcpart)
    u16*   dist   = (u16*)ut;                     // [4][2048][2048] u16 keys (32 MB)
    float* fcpart = ut;                           // [16][16][<=3072] f32
    int*   idx    = (int*)  (ws + 134217728);     // [32768][20]
    float* sqn    = (float*)(ws + 136839168);     // [32768]
    u16*   Bth    = (u16*)(ws + 136970240);       // [<=1024][<=512] bf16   1 MB
    u16*   Btl    = (u16*)(ws + 138018816);       // 1 MB
    float* bt     = (float*)(ws + 139067392);     // [<=1024]
    float* gpart  = (float*)(ws + 139071488);     // [256][1024]            1 MB
    float* feat   = (float*)(ws + 140120064);     // [16][1024]
    float* h1     = (float*)(ws + 140185600);
    float* h2     = (float*)(ws + 140251136);
    float* coarse = (float*)(ws + 140316672);     // [16][3072]
    float* pA     = (float*)(ws + 140513280);     // [512]
    float* pB     = (float*)(ws + 140515328);     // [512]
    float* wtf    = (float*)Bth;                  // conv1 fp32 wt alias

    // ---- conv1: C=3 (direct-coord knn, direct K=3 GEMM) ----
    select3_kernel<<<2048, 256, 0, stream>>>(corrupted, idx);
    wt_kernel<<<2, 256, 0, stream>>>(w1, b1, wtf, bt, 3, 64);
    conv1_kernel<<<16384, 256, 0, stream>>>(corrupted, wtf, bt, ut);
    gather_max_kernel<64><<<8192, 256, 0, stream>>>(ut, idx, cathi, catlo, 0, sqn);

    // ---- convs 2-4: symmetric MFMA gram (u16 keys) + select + edge GEMM + gather ----
    auto conv = [&](int coloff, int C, int Cout, const float* w, const float* bias, int colout,
                    bool needNextSqn) {
        int N2 = 2 * Cout;
        prep_edge_B<<<(N2 * C + 255) / 256, 256, 0, stream>>>(w, bias, Bth, Btl, bt, C, Cout);
        for (int g = 0; g < 4; ++g) {
            size_t off = ((size_t)g * 4 * N_) * 512 + coloff;
            mfma_gemm<2><<<dim3(136, 1, 4), 256, 0, stream>>>(
                cathi + off, catlo + off, (long long)N_ * 512, 512,
                cathi + off, catlo + off, (long long)N_ * 512, 512,
                sqn + (size_t)g * 4 * N_, N_,
                (float*)dist, (long long)(N_ * N_ / 2), N_, C);   // outZ in f32 units: u16 slice = N*N/2 f32
            select_kernel<<<2048, 256, 0, stream>>>(dist, idx + (size_t)g * 4 * N_ * KNN);
        }
        mfma_gemm<0><<<dim3(256, N2 / 128, 1), 256, 0, stream>>>(
            cathi + coloff, catlo + coloff, 0, 512,
            Bth, Btl, 0, C,
            bt, 0,
            ut, 0, N2, C);
        float* sq = needNextSqn ? sqn : nullptr;
        if (Cout == 64)       gather_max_kernel<64><<<8192, 256, 0, stream>>>(ut, idx, cathi, catlo, colout, sq);
        else if (Cout == 128) gather_max_kernel<128><<<16384, 256, 0, stream>>>(ut, idx, cathi, catlo, colout, sq);
        else                  gather_max_kernel<256><<<32768, 256, 0, stream>>>(ut, idx, cathi, catlo, colout, sq);
    };
    conv(0, 64, 64, w2, b2, 64, true);
    conv(64, 64, 128, w3, b3, 128, true);
    conv(128, 128, 256, w4, b4, 256, false);

    // ---- w5 + leaky + max over N (fused epilogue) ----
    prep_w5_kernel<<<2048, 256, 0, stream>>>(w5, Bth, Btl);
    mfma_gemm<1><<<dim3(256, 8, 1), 256, 0, stream>>>(
        cathi, catlo, 0, 512,
        Bth, Btl, 0, 512,
        b5, 0,
        gpart, 0, 1024, 512);
    featmax_kernel<<<64, 256, 0, stream>>>(gpart, feat);

    // ---- FCs: k-split partials + reduce (deterministic) ----
    fc_part_kernel<<<dim3(16, 16), 256, 0, stream>>>(feat, fw1, fcpart, 1024);
    fc_reduce_kernel<<<64, 256, 0, stream>>>(fcpart, fb1, h1, 1024, 1);
    fc_part_kernel<<<dim3(16, 16), 256, 0, stream>>>(h1, fw2, fcpart, 1024);
    fc_reduce_kernel<<<64, 256, 0, stream>>>(fcpart, fb2, h2, 1024, 1);
    fc_part_kernel<<<dim3(48, 16), 256, 0, stream>>>(h2, fw3, fcpart, 3072);
    fc_reduce_kernel<<<192, 256, 0, stream>>>(fcpart, fb3, coarse, 3072, 0);

    chamferA_kernel<<<dim3(16, 32), 256, 0, stream>>>(coarse, pts, pA);
    chamferB_kernel<<<dim3(16, 32), 256, 0, stream>>>(coarse, pts, pB);
    loss_kernel<<<1, 256, 0, stream>>>(pA, pB, out);
}

// Round 14
// 608.091 us; speedup vs baseline: 1.2782x; 1.1844x over previous
//
#include <hip/hip_runtime.h>
#include <float.h>

#define B_ 16
#define N_ 2048
#define KNN 20

typedef unsigned short u16;
typedef __attribute__((ext_vector_type(8))) short bf16x8;
typedef __attribute__((ext_vector_type(4))) float f32x4;

typedef const __attribute__((address_space(1))) unsigned gas_t;
typedef __attribute__((address_space(3))) unsigned las_t;

__device__ inline u16 bfhi(float v) {
    union { float f; unsigned u; } x; x.f = v;
    unsigned r = x.u + 0x7FFFu + ((x.u >> 16) & 1u);
    return (u16)(r >> 16);
}
__device__ inline u16 bflo(float v, u16 h) {
    union { unsigned u; float f; } y; y.u = ((unsigned)h) << 16;
    return bfhi(v - y.f);
}
__device__ inline unsigned fkey(float v) {
    union { float f; unsigned u; } x;
    x.f = fmaxf(v, 0.f);
    return x.u & 0x7FFFFFFFu;
}
__device__ inline u16 fkey16(float v) { return (u16)(fkey(v) >> 15); }
__device__ inline unsigned umin_(unsigned a, unsigned b) { return a < b ? a : b; }

// payload (element index) encoding per keys-per-lane layout
template <int MODE>
__device__ inline unsigned payof(int i, int lane) {
    if (MODE == 0) return ((unsigned)(i >> 2) << 8) + (unsigned)lane * 4u + (unsigned)(i & 3);
    else           return ((unsigned)(i >> 3) << 9) + (unsigned)lane * 8u + (unsigned)(i & 7);
}

// ---------------- bitonic sort across 64 lanes (ascending by key) ----------------
template <bool P>
__device__ inline void bitonic64(unsigned& key, unsigned& pay, int lane) {
#pragma unroll
    for (int k = 2; k <= 64; k <<= 1) {
#pragma unroll
        for (int j = k >> 1; j > 0; j >>= 1) {
            unsigned ok = __shfl_xor(key, j);
            unsigned op = P ? __shfl_xor(pay, j) : 0u;
            bool up = ((lane & k) == 0);
            bool lower = ((lane & j) == 0);
            bool takeOther = (up == lower) ? (ok < key) : (ok > key);
            if (takeOther) { key = ok; if (P) pay = op; }
        }
    }
}

// ---------------- top-20-smallest via threshold filter ----------------
template <int MODE>
__device__ inline void select20(const unsigned* kr, int lane,
                                unsigned* klist, unsigned* ilist,
                                int* __restrict__ outIdx) {
    unsigned lm = kr[0];
#pragma unroll
    for (int i = 1; i < 32; ++i) lm = umin_(lm, kr[i]);
    unsigned dummy = 0, sk = lm;
    bitonic64<false>(sk, dummy, lane);
    unsigned S = __shfl(sk, 19);
    unsigned c = 0;
#pragma unroll
    for (int i = 0; i < 32; ++i) c += (kr[i] <= S) ? 1u : 0u;
    unsigned incl = c;
#pragma unroll
    for (int d = 1; d < 64; d <<= 1) {
        unsigned t = __shfl_up(incl, d);
        if (lane >= d) incl += t;
    }
    unsigned stot = __shfl(incl, 63);
    unsigned pos = incl - c;
    klist[lane] = 0xFFFFFFFFu;
    __syncthreads();
#pragma unroll
    for (int i = 0; i < 32; ++i) {
        if (kr[i] <= S) {
            if (pos < 64u) {
                klist[pos] = kr[i];
                ilist[pos] = payof<MODE>(i, lane);
            }
            ++pos;
        }
    }
    __syncthreads();
    if (stot <= 64u) {
        unsigned key = klist[lane], pay = ilist[lane];
        bitonic64<true>(key, pay, lane);
        if (lane < KNN) outIdx[lane] = (int)pay;
    } else {
        unsigned taken = 0;
        for (int it = 0; it < KNN; ++it) {
            unsigned bk = 0xFFFFFFFFu; int bi = 0;
#pragma unroll
            for (int i = 0; i < 32; ++i) {
                bool better = (((taken >> i) & 1u) == 0u) && (kr[i] < bk);
                if (better) { bk = kr[i]; bi = i; }
            }
            unsigned bl = (unsigned)lane;
#pragma unroll
            for (int off = 32; off > 0; off >>= 1) {
                unsigned ok = __shfl_down(bk, off);
                unsigned ol = __shfl_down(bl, off);
                int oi = __shfl_down(bi, off);
                if (ok < bk) { bk = ok; bl = ol; bi = oi; }
            }
            bl = __shfl(bl, 0); bi = __shfl(bi, 0);
            if (lane == (int)bl) taken |= (1u << bi);
            if (lane == 0) outIdx[it] = (int)payof<MODE>(bi, (int)bl);
        }
    }
}

// select for convs 2-4: reads precomputed u16 keys (8 keys/lane/chunk)
__launch_bounds__(256)
__global__ void select_kernel(const u16* __restrict__ dist, int* __restrict__ idx_out) {
    __shared__ unsigned kl[4][64], il[4][64];
    int tid = threadIdx.x, w = tid >> 6, lane = tid & 63;
    size_t q = (size_t)blockIdx.x * 4 + w;
    const u16* src = dist + q * N_;
    unsigned kr[32];
#pragma unroll
    for (int j = 0; j < 4; ++j) {
        uint4 v = *(const uint4*)&src[j * 512 + lane * 8];
        const unsigned* pw = (const unsigned*)&v;
#pragma unroll
        for (int e = 0; e < 4; ++e) {
            kr[j * 8 + 2 * e]     = pw[e] & 0xFFFFu;
            kr[j * 8 + 2 * e + 1] = pw[e] >> 16;
        }
    }
    select20<1>(kr, lane, kl[w], il[w], idx_out + q * KNN);
}

// select for conv1: distances straight from 3-D coords; 16 queries per block
__launch_bounds__(256)
__global__ void select3_kernel(const float* __restrict__ x, int* __restrict__ idx_out) {
    __shared__ __align__(16) float cx[N_], cy[N_], cz[N_];
    __shared__ unsigned kl[4][64], il[4][64];
    int tid = threadIdx.x, blk = blockIdx.x;
    int b = blk >> 7, n0 = (blk & 127) * 16;
    for (int i = tid; i < N_; i += 256) {
        const float* p = x + (size_t)(b * N_ + i) * 3;
        cx[i] = p[0]; cy[i] = p[1]; cz[i] = p[2];
    }
    __syncthreads();
    int w = tid >> 6, lane = tid & 63;
    for (int r = 0; r < 4; ++r) {
        int q = n0 + r * 4 + w;
        float qx = cx[q], qy = cy[q], qz = cz[q];
        unsigned kr[32];
#pragma unroll
        for (int j = 0; j < 8; ++j) {
            float4 vx = *(const float4*)&cx[j * 256 + lane * 4];
            float4 vy = *(const float4*)&cy[j * 256 + lane * 4];
            float4 vz = *(const float4*)&cz[j * 256 + lane * 4];
            float dx, dy, dz;
            dx = qx - vx.x; dy = qy - vy.x; dz = qz - vz.x;
            kr[j * 4 + 0] = fkey(fmaf(dx, dx, fmaf(dy, dy, dz * dz)));
            dx = qx - vx.y; dy = qy - vy.y; dz = qz - vz.y;
            kr[j * 4 + 1] = fkey(fmaf(dx, dx, fmaf(dy, dy, dz * dz)));
            dx = qx - vx.z; dy = qy - vy.z; dz = qz - vz.z;
            kr[j * 4 + 2] = fkey(fmaf(dx, dx, fmaf(dy, dy, dz * dz)));
            dx = qx - vx.w; dy = qy - vy.w; dz = qz - vz.w;
            kr[j * 4 + 3] = fkey(fmaf(dx, dx, fmaf(dy, dy, dz * dz)));
        }
        select20<0>(kr, lane, kl[w], il[w], idx_out + ((size_t)(b * N_ + q)) * KNN);
    }
}

// ---------------- weight prep ----------------
__global__ void wt_kernel(const float* __restrict__ w, const float* __restrict__ b,
                          float* __restrict__ wt, float* __restrict__ bt,
                          int C, int Cout) {
    int N2 = 2 * Cout;
    int t = blockIdx.x * 256 + threadIdx.x;
    if (t < C * N2) {
        int c = t / N2, d = t % N2;
        float v;
        if (d < Cout) v = w[c * Cout + d];
        else          v = w[(C + c) * Cout + (d - Cout)] - w[c * Cout + (d - Cout)];
        wt[t] = v;
    }
    if (t < N2) bt[t] = (t < Cout) ? 0.f : b[t - Cout];
}

__global__ void prep_edge_B(const float* __restrict__ w, const float* __restrict__ b,
                            u16* __restrict__ Bth, u16* __restrict__ Btl,
                            float* __restrict__ bt, int C, int Cout) {
    int N2 = 2 * Cout;
    int t = blockIdx.x * 256 + threadIdx.x;
    if (t < N2 * C) {
        int d = t / C, c = t % C;
        float v = (d < Cout) ? w[c * Cout + d]
                             : (w[(C + c) * Cout + (d - Cout)] - w[c * Cout + (d - Cout)]);
        u16 h = bfhi(v);
        Bth[t] = h; Btl[t] = bflo(v, h);
    }
    if (t < N2) bt[t] = (t < Cout) ? 0.f : b[t - Cout];
}

__global__ void prep_w5_kernel(const float* __restrict__ w5,
                               u16* __restrict__ Bth, u16* __restrict__ Btl) {
    int t = blockIdx.x * 256 + threadIdx.x;   // 1024*512
    int n = t / 512, k = t % 512;
    float v = w5[(size_t)k * 1024 + n];
    u16 h = bfhi(v);
    Bth[t] = h; Btl[t] = bflo(v, h);
}

// ---------------- split-bf16 MFMA GEMM, 128x128 tile, 4 waves (2x2) ----------------
// Staging: global_load_lds width=16, linear LDS, XOR-swizzled granule.
// EPI 0/1: split-3 product, bijective XCD-chunked block mapping.
// EPI=2: u16 dist keys, split-3. EPI=3: u16 dist keys, HI-ONLY product (1 MFMA).
template <int EPI>
__launch_bounds__(256, 2)
__global__ void mfma_gemm(const u16* __restrict__ Ah, const u16* __restrict__ Al,
                          long long aZ, int lda,
                          const u16* __restrict__ Bh, const u16* __restrict__ Bl,
                          long long bZ, int ldb,
                          const float* __restrict__ ep, long long epZ,
                          float* __restrict__ out, long long outZ, int ldo,
                          int K) {
    __shared__ __align__(16) char smem[73728];
    u16* AsH = (u16*)(smem);
    u16* AsL = (u16*)(smem + 16384);
    u16* BsH = (u16*)(smem + 32768);
    u16* BsL = (u16*)(smem + 49152);
    u16 (*LTs)[136] = (u16(*)[136])(smem);   // alias, used post-loop (EPI>=2)
    __shared__ float red[2][128];
    int tid = threadIdx.x;
    int m0, n0, mt = 0;
    if (EPI >= 2) {
        int t = blockIdx.x, rem = 16, bi = 0;
        while (t >= rem) { t -= rem; ++bi; --rem; }
        m0 = bi * 128; n0 = (bi + t) * 128;
    } else {
        int MT = gridDim.x, NT = gridDim.y;
        int f = blockIdx.x + blockIdx.y * MT;
        int xcd = f & 7, s = f >> 3;
        int sm = s / NT;
        int nt = s - sm * NT;
        mt = xcd * (MT >> 3) + sm;
        m0 = mt * 128; n0 = nt * 128;
    }
    int z = blockIdx.z;
    const u16* ah = Ah + (size_t)z * aZ;
    const u16* al = Al + (size_t)z * aZ;
    const u16* bh = Bh + (size_t)z * bZ;
    const u16* bl = Bl + (size_t)z * bZ;
    const float* epz = ep + (size_t)z * epZ;
    float* op = out + (size_t)z * outZ;

    int wid = tid >> 6, lane = tid & 63;
    int wm = wid >> 1, wn = wid & 1;
    int l15 = lane & 15, l4 = lane >> 4;
    int lrow8 = lane >> 3;
    int lg = lane & 7;

    f32x4 acc[4][4];
#pragma unroll
    for (int i = 0; i < 4; ++i)
#pragma unroll
        for (int j = 0; j < 4; ++j) acc[i][j] = (f32x4){0.f, 0.f, 0.f, 0.f};

    for (int k0 = 0; k0 < K; k0 += 64) {
        if (k0) __syncthreads();
#pragma unroll
        for (int ch = 0; ch < 4; ++ch) {
            int row = wid * 32 + ch * 8 + lrow8;
            int gsrc = lg ^ (row & 7);
            unsigned ldsoff = (unsigned)(wid * 32 + ch * 8) * 64;
            size_t ga = (size_t)(m0 + row) * lda + k0 + gsrc * 8;
            size_t gb = (size_t)(n0 + row) * ldb + k0 + gsrc * 8;
            __builtin_amdgcn_global_load_lds((gas_t*)(ah + ga), (las_t*)(AsH + ldsoff), 16, 0, 0);
            __builtin_amdgcn_global_load_lds((gas_t*)(bh + gb), (las_t*)(BsH + ldsoff), 16, 0, 0);
            if (EPI != 3) {
                __builtin_amdgcn_global_load_lds((gas_t*)(al + ga), (las_t*)(AsL + ldsoff), 16, 0, 0);
                __builtin_amdgcn_global_load_lds((gas_t*)(bl + gb), (las_t*)(BsL + ldsoff), 16, 0, 0);
            }
        }
        __syncthreads();
#pragma unroll
        for (int kk = 0; kk < 2; ++kk) {
            int ko_g = kk * 4 + l4;
            bf16x8 aH[4], aL[4], bH[4], bL[4];
#pragma unroll
            for (int i = 0; i < 4; ++i) {
                int ra = wm * 64 + i * 16 + l15;
                int oa = ra * 64 + ((ko_g ^ (ra & 7)) << 3);
                aH[i] = *(const bf16x8*)&AsH[oa];
                int rb = wn * 64 + i * 16 + l15;
                int ob = rb * 64 + ((ko_g ^ (rb & 7)) << 3);
                bH[i] = *(const bf16x8*)&BsH[ob];
                if (EPI != 3) {
                    aL[i] = *(const bf16x8*)&AsL[oa];
                    bL[i] = *(const bf16x8*)&BsL[ob];
                }
            }
#pragma unroll
            for (int i = 0; i < 4; ++i)
#pragma unroll
                for (int j = 0; j < 4; ++j) {
                    acc[i][j] = __builtin_amdgcn_mfma_f32_16x16x32_bf16(aH[i], bH[j], acc[i][j], 0, 0, 0);
                    if (EPI != 3) {
                        acc[i][j] = __builtin_amdgcn_mfma_f32_16x16x32_bf16(aH[i], bL[j], acc[i][j], 0, 0, 0);
                        acc[i][j] = __builtin_amdgcn_mfma_f32_16x16x32_bf16(aL[i], bH[j], acc[i][j], 0, 0, 0);
                    }
                }
        }
    }

    if (EPI == 0) {
#pragma unroll
        for (int i = 0; i < 4; ++i)
#pragma unroll
            for (int r = 0; r < 4; ++r) {
                int grow = m0 + wm * 64 + i * 16 + l4 * 4 + r;
#pragma unroll
                for (int j = 0; j < 4; ++j) {
                    int col = n0 + wn * 64 + j * 16 + l15;
                    op[(size_t)grow * ldo + col] = acc[i][j][r] + epz[col];
                }
            }
    } else if (EPI == 1) {
        float pm[4];
#pragma unroll
        for (int j = 0; j < 4; ++j) {
            float v = -FLT_MAX;
#pragma unroll
            for (int i = 0; i < 4; ++i)
#pragma unroll
                for (int r = 0; r < 4; ++r) v = fmaxf(v, acc[i][j][r]);
            v = fmaxf(v, __shfl_xor(v, 16));
            v = fmaxf(v, __shfl_xor(v, 32));
            pm[j] = v;
        }
        if (l4 == 0) {
#pragma unroll
            for (int j = 0; j < 4; ++j) red[wm][wn * 64 + j * 16 + l15] = pm[j];
        }
        __syncthreads();
        if (tid < 128) {
            float v = fmaxf(red[0][tid], red[1][tid]) + epz[n0 + tid];
            v = (v > 0.f) ? v : 0.2f * v;
            op[(size_t)mt * ldo + n0 + tid] = v;
        }
    } else {
        u16* opu = (u16*)op;
#pragma unroll
        for (int i = 0; i < 4; ++i)
#pragma unroll
            for (int r = 0; r < 4; ++r) {
                int grow = m0 + wm * 64 + i * 16 + l4 * 4 + r;
                float sm = epz[grow];
#pragma unroll
                for (int j = 0; j < 4; ++j) {
                    int col = n0 + wn * 64 + j * 16 + l15;
                    opu[(size_t)grow * ldo + col] = fkey16(sm + epz[col] - 2.f * acc[i][j][r]);
                }
            }
        if (m0 != n0) {
            __syncthreads();   // staging LDS dead; safe to reuse as LTs
#pragma unroll
            for (int i = 0; i < 4; ++i)
#pragma unroll
                for (int j = 0; j < 4; ++j) {
                    int colL  = wn * 64 + j * 16 + l15;
                    int growL = wm * 64 + i * 16 + l4 * 4;
                    unsigned k0v = fkey16(epz[m0 + growL + 0] + epz[n0 + colL] - 2.f * acc[i][j][0]);
                    unsigned k1v = fkey16(epz[m0 + growL + 1] + epz[n0 + colL] - 2.f * acc[i][j][1]);
                    unsigned k2v = fkey16(epz[m0 + growL + 2] + epz[n0 + colL] - 2.f * acc[i][j][2]);
                    unsigned k3v = fkey16(epz[m0 + growL + 3] + epz[n0 + colL] - 2.f * acc[i][j][3]);
                    uint2 pk;
                    pk.x = k0v | (k1v << 16);
                    pk.y = k2v | (k3v << 16);
                    *(uint2*)&LTs[colL][growL] = pk;
                }
            __syncthreads();
            for (int rr0 = 0; rr0 < 128; rr0 += 8) {
                int rr = rr0 + (tid >> 5), cc = (tid & 31) * 4;
                uint2 v = *(const uint2*)&LTs[rr][cc];
                *(uint2*)&opu[(size_t)(n0 + rr) * ldo + m0 + cc] = v;
            }
        }
    }
}

// ---------------- conv1 direct GEMM (K=3) ----------------
__global__ void conv1_kernel(const float* __restrict__ x, const float* __restrict__ wt,
                             const float* __restrict__ bt, float* __restrict__ ut) {
    __shared__ float sw[3][128], sb[128];
    int tid = threadIdx.x;
    if (tid < 128) { sw[0][tid] = wt[tid]; sw[1][tid] = wt[128 + tid]; }
    else { int d = tid - 128; sw[2][d] = wt[256 + d]; sb[d] = bt[d]; }
    __syncthreads();
    int t = blockIdx.x * 256 + tid;
    int m = t >> 7, d = t & 127;
    const float* xm = x + (size_t)m * 3;
    float v = sb[d];
    v = fmaf(xm[0], sw[0][d], v);
    v = fmaf(xm[1], sw[1][d], v);
    v = fmaf(xm[2], sw[2][d], v);
    ut[(size_t)m * 128 + d] = v;
}

// ---------------- gather + leaky + max over k + fused next-conv sqnorm ----------------
template <int COUT>
__global__ void gather_max_kernel(const float* __restrict__ ut,
                                  const int* __restrict__ idx,
                                  u16* __restrict__ cathi, u16* __restrict__ catlo,
                                  int coloff, float* __restrict__ sqn_out) {
    const int P = 256 / COUT;
    int tid = threadIdx.x;
    int p = tid / COUT, d = tid % COUT;
    int nb = gridDim.x;
    int i = blockIdx.x;
    int half = (i >= (nb >> 1)) ? 1 : 0;
    int ii = i - half * (nb >> 1);
    int b = half * 8 + (ii & 7);
    int within = ii >> 3;
    int pt_base = b * 2048 + within * P;
    int pt = pt_base + p;
    int n = pt & 2047;
    __shared__ int sidx[P][KNN];
    __shared__ float wpart[4];
    for (int q = tid; q < P * KNN; q += 256) {
        int pp = q / KNN, kk = q % KNN;
        sidx[pp][kk] = idx[(size_t)(pt_base + pp) * KNN + kk];
    }
    __syncthreads();
    const int N2 = 2 * COUT;
    const float* utb = ut + (size_t)b * N_ * N2;
    float tval = utb[(size_t)n * N2 + COUT + d];
    float acc = -FLT_MAX;
#pragma unroll
    for (int k = 0; k < KNN; k++) {
        int j = __builtin_amdgcn_readfirstlane(sidx[p][k]);
        const float* rp = utb + (size_t)j * N2;
        float s = rp[d] + tval;
        s = (s > 0.f) ? s : 0.2f * s;
        acc = fmaxf(acc, s);
    }
    u16 h = bfhi(acc);
    u16 l = bflo(acc, h);
    cathi[(size_t)pt * 512 + coloff + d] = h;
    catlo[(size_t)pt * 512 + coloff + d] = l;
    if (sqn_out) {
        union { unsigned u; float f; } va, vb;
        va.u = ((unsigned)h) << 16; vb.u = ((unsigned)l) << 16;
        float v = va.f + vb.f;
        float sq = v * v;
#pragma unroll
        for (int off = 1; off < 64; off <<= 1) sq += __shfl_xor(sq, off);
        int wid = tid >> 6, lane = tid & 63;
        if (lane == 0) wpart[wid] = sq;
        __syncthreads();
        const int WPP = COUT / 64;
        if (tid < P) {
            float s2 = 0.f;
#pragma unroll
            for (int ww = 0; ww < WPP; ++ww) s2 += wpart[tid * WPP + ww];
            sqn_out[pt_base + tid] = s2;
        }
    }
}

// ---------------- feat = max over 16 row-blocks of gpart ----------------
__global__ void featmax_kernel(const float* __restrict__ gpart, float* __restrict__ feat) {
    int t = blockIdx.x * 256 + threadIdx.x;   // 16*1024
    int b = t >> 10, d = t & 1023;
    float m = -FLT_MAX;
    for (int rb = 0; rb < 16; ++rb)
        m = fmaxf(m, gpart[(size_t)(b * 16 + rb) * 1024 + d]);
    feat[t] = m;
}

// ---------------- FC k-split: partials over 64-k chunks; W read exactly once ----------------
__global__ void fc_part_kernel(const float* __restrict__ in, const float* __restrict__ W,
                               float* __restrict__ part, int N) {
    __shared__ float sin_[16][64];
    __shared__ float red[3][16][64];
    int tid = threadIdx.x, lane = tid & 63, g = tid >> 6;
    int col = blockIdx.x * 64 + lane;
    int k0 = blockIdx.y * 64;
    for (int i = tid; i < 1024; i += 256)
        sin_[i >> 6][i & 63] = in[(i >> 6) * 1024 + k0 + (i & 63)];
    __syncthreads();
    float acc[16];
#pragma unroll
    for (int b = 0; b < 16; ++b) acc[b] = 0.f;
    int kk0 = g * 16;
#pragma unroll
    for (int k = kk0; k < kk0 + 16; ++k) {
        float wv = W[(size_t)(k0 + k) * N + col];
#pragma unroll
        for (int b = 0; b < 16; ++b) acc[b] = fmaf(sin_[b][k], wv, acc[b]);
    }
    if (g) {
#pragma unroll
        for (int b = 0; b < 16; ++b) red[g - 1][b][lane] = acc[b];
    }
    __syncthreads();
    if (g == 0) {
#pragma unroll
        for (int b = 0; b < 16; ++b) {
            float v = acc[b] + red[0][b][lane] + red[1][b][lane] + red[2][b][lane];
            part[((size_t)blockIdx.y * 16 + b) * N + col] = v;
        }
    }
}

__global__ void fc_reduce_kernel(const float* __restrict__ part, const float* __restrict__ bias,
                                 float* __restrict__ out, int N, int act) {
    int t = blockIdx.x * 256 + threadIdx.x;
    int b = t / N, col = t % N;
    float s = bias[col];
#pragma unroll
    for (int ks = 0; ks < 16; ++ks) s += part[((size_t)ks * 16 + b) * N + col];
    if (act) s = fmaxf(s, 0.f);
    out[(size_t)b * N + col] = s;
}

// ---------------- chamfer pass A ----------------
__launch_bounds__(256)
__global__ void chamferA_kernel(const float* __restrict__ coarse,
                                const float* __restrict__ pts,
                                float* __restrict__ pA) {
    __shared__ float spx[2048], spy[2048], spz[2048];
    __shared__ float red[4];
    int b = blockIdx.x, ch = blockIdx.y, tid = threadIdx.x;
    const float* pb = pts + (size_t)b * 6144;
    for (int i = tid; i < 2048; i += 256) {
        spx[i] = pb[i * 3]; spy[i] = pb[i * 3 + 1]; spz[i] = pb[i * 3 + 2];
    }
    __syncthreads();
    int q = ch * 32 + (tid >> 3);
    int oct = tid & 7;
    const float* cp = coarse + (size_t)b * 3072 + q * 3;
    float cx = cp[0], cy = cp[1], cz = cp[2];
    float mn0 = FLT_MAX, mn1 = FLT_MAX, mn2 = FLT_MAX, mn3 = FLT_MAX;
    int n0 = oct * 256;
    for (int n = n0; n < n0 + 256; n += 4) {
        float dx, dy, dz;
        dx = cx - spx[n];     dy = cy - spy[n];     dz = cz - spz[n];
        mn0 = fminf(mn0, fmaf(dx, dx, fmaf(dy, dy, dz * dz)));
        dx = cx - spx[n + 1]; dy = cy - spy[n + 1]; dz = cz - spz[n + 1];
        mn1 = fminf(mn1, fmaf(dx, dx, fmaf(dy, dy, dz * dz)));
        dx = cx - spx[n + 2]; dy = cy - spy[n + 2]; dz = cz - spz[n + 2];
        mn2 = fminf(mn2, fmaf(dx, dx, fmaf(dy, dy, dz * dz)));
        dx = cx - spx[n + 3]; dy = cy - spy[n + 3]; dz = cz - spz[n + 3];
        mn3 = fminf(mn3, fmaf(dx, dx, fmaf(dy, dy, dz * dz)));
    }
    float mn = fminf(fminf(mn0, mn1), fminf(mn2, mn3));
    mn = fminf(mn, __shfl_xor(mn, 1));
    mn = fminf(mn, __shfl_xor(mn, 2));
    mn = fminf(mn, __shfl_xor(mn, 4));
    float s = (oct == 0) ? mn : 0.f;
#pragma unroll
    for (int off = 32; off > 0; off >>= 1) s += __shfl_down(s, off);
    int w = tid >> 6, lane = tid & 63;
    if (lane == 0) red[w] = s;
    __syncthreads();
    if (tid == 0) pA[b * 32 + ch] = red[0] + red[1] + red[2] + red[3];
}

// ---------------- chamfer pass B ----------------
__launch_bounds__(256)
__global__ void chamferB_kernel(const float* __restrict__ coarse,
                                const float* __restrict__ pts,
                                float* __restrict__ pB) {
    __shared__ float scx[1024], scy[1024], scz[1024];
    __shared__ float red[4];
    int b = blockIdx.x, ch = blockIdx.y, tid = threadIdx.x;
    const float* cb = coarse + (size_t)b * 3072;
    for (int i = tid; i < 1024; i += 256) {
        scx[i] = cb[i * 3]; scy[i] = cb[i * 3 + 1]; scz[i] = cb[i * 3 + 2];
    }
    __syncthreads();
    int p = ch * 64 + (tid >> 2);
    int quad = tid & 3;
    const float* pp = pts + (size_t)b * 6144 + p * 3;
    float px = pp[0], py = pp[1], pz = pp[2];
    float mn0 = FLT_MAX, mn1 = FLT_MAX, mn2 = FLT_MAX, mn3 = FLT_MAX;
    int m0 = quad * 256;
    for (int m = m0; m < m0 + 256; m += 4) {
        float dx, dy, dz;
        dx = px - scx[m];     dy = py - scy[m];     dz = pz - scz[m];
        mn0 = fminf(mn0, fmaf(dx, dx, fmaf(dy, dy, dz * dz)));
        dx = px - scx[m + 1]; dy = py - scy[m + 1]; dz = pz - scz[m + 1];
        mn1 = fminf(mn1, fmaf(dx, dx, fmaf(dy, dy, dz * dz)));
        dx = px - scx[m + 2]; dy = py - scy[m + 2]; dz = pz - scz[m + 2];
        mn2 = fminf(mn2, fmaf(dx, dx, fmaf(dy, dy, dz * dz)));
        dx = px - scx[m + 3]; dy = py - scy[m + 3]; dz = pz - scz[m + 3];
        mn3 = fminf(mn3, fmaf(dx, dx, fmaf(dy, dy, dz * dz)));
    }
    float mn = fminf(fminf(mn0, mn1), fminf(mn2, mn3));
    mn = fminf(mn, __shfl_xor(mn, 1));
    mn = fminf(mn, __shfl_xor(mn, 2));
    float s = (quad == 0) ? mn : 0.f;
#pragma unroll
    for (int off = 32; off > 0; off >>= 1) s += __shfl_down(s, off);
    int w = tid >> 6, lane = tid & 63;
    if (lane == 0) red[w] = s;
    __syncthreads();
    if (tid == 0) pB[b * 32 + ch] = red[0] + red[1] + red[2] + red[3];
}

__global__ void loss_kernel(const float* __restrict__ pA, const float* __restrict__ pB,
                            float* __restrict__ out) {
    __shared__ float rA[4], rB[4];
    int tid = threadIdx.x;   // 256
    float a = pA[tid] + pA[tid + 256];
    float b = pB[tid] + pB[tid + 256];
#pragma unroll
    for (int off = 32; off > 0; off >>= 1) {
        a += __shfl_down(a, off);
        b += __shfl_down(b, off);
    }
    int w = tid >> 6, lane = tid & 63;
    if (lane == 0) { rA[w] = a; rB[w] = b; }
    __syncthreads();
    if (tid == 0)
        out[0] = (rA[0] + rA[1] + rA[2] + rA[3]) / (16.f * 1024.f)
               + (rB[0] + rB[1] + rB[2] + rB[3]) / (16.f * 2048.f);
}

extern "C" void kernel_launch(void* const* d_in, const int* in_sizes, int n_in,
                              void* d_out, int out_size, void* d_ws, size_t ws_size,
                              hipStream_t stream) {
    const float* corrupted = (const float*)d_in[0];
    const float* pts = (const float*)d_in[1];
    const float* w1 = (const float*)d_in[2];   const float* b1 = (const float*)d_in[3];
    const float* w2 = (const float*)d_in[4];   const float* b2 = (const float*)d_in[5];
    const float* w3 = (const float*)d_in[6];   const float* b3 = (const float*)d_in[7];
    const float* w4 = (const float*)d_in[8];   const float* b4 = (const float*)d_in[9];
    const float* w5 = (const float*)d_in[10];  const float* b5 = (const float*)d_in[11];
    const float* fw1 = (const float*)d_in[12]; const float* fb1 = (const float*)d_in[13];
    const float* fw2 = (const float*)d_in[14]; const float* fb2 = (const float*)d_in[15];
    const float* fw3 = (const float*)d_in[16]; const float* fb3 = (const float*)d_in[17];
    float* out = (float*)d_out;

    char* ws = (char*)d_ws;
    u16*   cathi  = (u16*)(ws);                   // [32768][512] bf16 hi   32 MB
    u16*   catlo  = (u16*)(ws + 33554432);        // [32768][512] bf16 lo   32 MB
    float* ut     = (float*)(ws + 67108864);      // [32768][<=512] f32     64 MB (aliased dist/fcpart)
    u16*   dist   = (u16*)ut;                     // [8][2048][2048] u16 keys (64 MB)
    float* fcpart = ut;                           // [16][16][<=3072] f32
    int*   idx    = (int*)  (ws + 134217728);     // [32768][20]
    float* sqn    = (float*)(ws + 136839168);     // [32768]
    u16*   Bth    = (u16*)(ws + 136970240);       // [<=1024][<=512] bf16   1 MB
    u16*   Btl    = (u16*)(ws + 138018816);       // 1 MB
    float* bt     = (float*)(ws + 139067392);     // [<=1024]
    float* gpart  = (float*)(ws + 139071488);     // [256][1024]            1 MB
    float* feat   = (float*)(ws + 140120064);     // [16][1024]
    float* h1     = (float*)(ws + 140185600);
    float* h2     = (float*)(ws + 140251136);
    float* coarse = (float*)(ws + 140316672);     // [16][3072]
    float* pA     = (float*)(ws + 140513280);     // [512]
    float* pB     = (float*)(ws + 140515328);     // [512]
    float* wtf    = (float*)Bth;                  // conv1 fp32 wt alias

    // ---- conv1: C=3 (direct-coord knn, direct K=3 GEMM) ----
    select3_kernel<<<2048, 256, 0, stream>>>(corrupted, idx);
    wt_kernel<<<2, 256, 0, stream>>>(w1, b1, wtf, bt, 3, 64);
    conv1_kernel<<<16384, 256, 0, stream>>>(corrupted, wtf, bt, ut);
    gather_max_kernel<64><<<8192, 256, 0, stream>>>(ut, idx, cathi, catlo, 0, sqn);

    // ---- convs 2-4: symmetric hi-only MFMA gram (u16 keys, 2 groups of z=8) ----
    auto conv = [&](int coloff, int C, int Cout, const float* w, const float* bias, int colout,
                    bool needNextSqn) {
        int N2 = 2 * Cout;
        prep_edge_B<<<(N2 * C + 255) / 256, 256, 0, stream>>>(w, bias, Bth, Btl, bt, C, Cout);
        for (int g = 0; g < 2; ++g) {
            size_t off = ((size_t)g * 8 * N_) * 512 + coloff;
            mfma_gemm<3><<<dim3(136, 1, 8), 256, 0, stream>>>(
                cathi + off, catlo + off, (long long)N_ * 512, 512,
                cathi + off, catlo + off, (long long)N_ * 512, 512,
                sqn + (size_t)g * 8 * N_, N_,
                (float*)dist, (long long)(N_ * N_ / 2), N_, C);   // outZ in f32 units (u16 slice)
            select_kernel<<<4096, 256, 0, stream>>>(dist, idx + (size_t)g * 8 * N_ * KNN);
        }
        mfma_gemm<0><<<dim3(256, N2 / 128, 1), 256, 0, stream>>>(
            cathi + coloff, catlo + coloff, 0, 512,
            Bth, Btl, 0, C,
            bt, 0,
            ut, 0, N2, C);
        float* sq = needNextSqn ? sqn : nullptr;
        if (Cout == 64)       gather_max_kernel<64><<<8192, 256, 0, stream>>>(ut, idx, cathi, catlo, colout, sq);
        else if (Cout == 128) gather_max_kernel<128><<<16384, 256, 0, stream>>>(ut, idx, cathi, catlo, colout, sq);
        else                  gather_max_kernel<256><<<32768, 256, 0, stream>>>(ut, idx, cathi, catlo, colout, sq);
    };
    conv(0, 64, 64, w2, b2, 64, true);
    conv(64, 64, 128, w3, b3, 128, true);
    conv(128, 128, 256, w4, b4, 256, false);

    // ---- w5 + leaky + max over N (fused epilogue) ----
    prep_w5_kernel<<<2048, 256, 0, stream>>>(w5, Bth, Btl);
    mfma_gemm<1><<<dim3(256, 8, 1), 256, 0, stream>>>(
        cathi, catlo, 0, 512,
        Bth, Btl, 0, 512,
        b5, 0,
        gpart, 0, 1024, 512);
    featmax_kernel<<<64, 256, 0, stream>>>(gpart, feat);

    // ---- FCs: k-split partials + reduce (deterministic) ----
    fc_part_kernel<<<dim3(16, 16), 256, 0, stream>>>(feat, fw1, fcpart, 1024);
    fc_reduce_kernel<<<64, 256, 0, stream>>>(fcpart, fb1, h1, 1024, 1);
    fc_part_kernel<<<dim3(16, 16), 256, 0, stream>>>(h1, fw2, fcpart, 1024);
    fc_reduce_kernel<<<64, 256, 0, stream>>>(fcpart, fb2, h2, 1024, 1);
    fc_part_kernel<<<dim3(48, 16), 256, 0, stream>>>(h2, fw3, fcpart, 3072);
    fc_reduce_kernel<<<192, 256, 0, stream>>>(fcpart, fb3, coarse, 3072, 0);

    chamferA_kernel<<<dim3(16, 32), 256, 0, stream>>>(coarse, pts, pA);
    chamferB_kernel<<<dim3(16, 32), 256, 0, stream>>>(coarse, pts, pB);
    loss_kernel<<<1, 256, 0, stream>>>(pA, pB, out);
}

// Round 15
// 582.539 us; speedup vs baseline: 1.3343x; 1.0439x over previous
//
#include <hip/hip_runtime.h>
#include <float.h>

#define B_ 16
#define N_ 2048
#define KNN 20

typedef unsigned short u16;
typedef __attribute__((ext_vector_type(8))) short bf16x8;
typedef __attribute__((ext_vector_type(4))) float f32x4;

typedef const __attribute__((address_space(1))) unsigned gas_t;
typedef __attribute__((address_space(3))) unsigned las_t;

__device__ inline u16 bfhi(float v) {
    union { float f; unsigned u; } x; x.f = v;
    unsigned r = x.u + 0x7FFFu + ((x.u >> 16) & 1u);
    return (u16)(r >> 16);
}
__device__ inline u16 bflo(float v, u16 h) {
    union { unsigned u; float f; } y; y.u = ((unsigned)h) << 16;
    return bfhi(v - y.f);
}
__device__ inline unsigned fkey(float v) {
    union { float f; unsigned u; } x;
    x.f = fmaxf(v, 0.f);
    return x.u & 0x7FFFFFFFu;
}
__device__ inline u16 fkey16(float v) { return (u16)(fkey(v) >> 15); }
__device__ inline unsigned umin_(unsigned a, unsigned b) { return a < b ? a : b; }

// payload (element index) encoding per keys-per-lane layout
template <int MODE>
__device__ inline unsigned payof(int i, int lane) {
    if (MODE == 0) return ((unsigned)(i >> 2) << 8) + (unsigned)lane * 4u + (unsigned)(i & 3);
    else           return ((unsigned)(i >> 3) << 9) + (unsigned)lane * 8u + (unsigned)(i & 7);
}

// ---------------- bitonic sort across 64 lanes (ascending by key) ----------------
template <bool P>
__device__ inline void bitonic64(unsigned& key, unsigned& pay, int lane) {
#pragma unroll
    for (int k = 2; k <= 64; k <<= 1) {
#pragma unroll
        for (int j = k >> 1; j > 0; j >>= 1) {
            unsigned ok = __shfl_xor(key, j);
            unsigned op = P ? __shfl_xor(pay, j) : 0u;
            bool up = ((lane & k) == 0);
            bool lower = ((lane & j) == 0);
            bool takeOther = (up == lower) ? (ok < key) : (ok > key);
            if (takeOther) { key = ok; if (P) pay = op; }
        }
    }
}

// ---------------- top-20-smallest via threshold filter ----------------
template <int MODE>
__device__ inline void select20(const unsigned* kr, int lane,
                                unsigned* klist, unsigned* ilist,
                                int* __restrict__ outIdx) {
    unsigned lm = kr[0];
#pragma unroll
    for (int i = 1; i < 32; ++i) lm = umin_(lm, kr[i]);
    unsigned dummy = 0, sk = lm;
    bitonic64<false>(sk, dummy, lane);
    unsigned S = __shfl(sk, 19);
    unsigned c = 0;
#pragma unroll
    for (int i = 0; i < 32; ++i) c += (kr[i] <= S) ? 1u : 0u;
    unsigned incl = c;
#pragma unroll
    for (int d = 1; d < 64; d <<= 1) {
        unsigned t = __shfl_up(incl, d);
        if (lane >= d) incl += t;
    }
    unsigned stot = __shfl(incl, 63);
    unsigned pos = incl - c;
    klist[lane] = 0xFFFFFFFFu;
    __syncthreads();
#pragma unroll
    for (int i = 0; i < 32; ++i) {
        if (kr[i] <= S) {
            if (pos < 64u) {
                klist[pos] = kr[i];
                ilist[pos] = payof<MODE>(i, lane);
            }
            ++pos;
        }
    }
    __syncthreads();
    if (stot <= 64u) {
        unsigned key = klist[lane], pay = ilist[lane];
        bitonic64<true>(key, pay, lane);
        if (lane < KNN) outIdx[lane] = (int)pay;
    } else {
        unsigned taken = 0;
        for (int it = 0; it < KNN; ++it) {
            unsigned bk = 0xFFFFFFFFu; int bi = 0;
#pragma unroll
            for (int i = 0; i < 32; ++i) {
                bool better = (((taken >> i) & 1u) == 0u) && (kr[i] < bk);
                if (better) { bk = kr[i]; bi = i; }
            }
            unsigned bl = (unsigned)lane;
#pragma unroll
            for (int off = 32; off > 0; off >>= 1) {
                unsigned ok = __shfl_down(bk, off);
                unsigned ol = __shfl_down(bl, off);
                int oi = __shfl_down(bi, off);
                if (ok < bk) { bk = ok; bl = ol; bi = oi; }
            }
            bl = __shfl(bl, 0); bi = __shfl(bi, 0);
            if (lane == (int)bl) taken |= (1u << bi);
            if (lane == 0) outIdx[it] = (int)payof<MODE>(bi, (int)bl);
        }
    }
}

// select for convs 2-4: reads precomputed u16 keys (8 keys/lane/chunk)
__launch_bounds__(256)
__global__ void select_kernel(const u16* __restrict__ dist, int* __restrict__ idx_out) {
    __shared__ unsigned kl[4][64], il[4][64];
    int tid = threadIdx.x, w = tid >> 6, lane = tid & 63;
    size_t q = (size_t)blockIdx.x * 4 + w;
    const u16* src = dist + q * N_;
    unsigned kr[32];
#pragma unroll
    for (int j = 0; j < 4; ++j) {
        uint4 v = *(const uint4*)&src[j * 512 + lane * 8];
        const unsigned* pw = (const unsigned*)&v;
#pragma unroll
        for (int e = 0; e < 4; ++e) {
            kr[j * 8 + 2 * e]     = pw[e] & 0xFFFFu;
            kr[j * 8 + 2 * e + 1] = pw[e] >> 16;
        }
    }
    select20<1>(kr, lane, kl[w], il[w], idx_out + q * KNN);
}

// select for conv1: distances straight from 3-D coords; 16 queries per block
__launch_bounds__(256)
__global__ void select3_kernel(const float* __restrict__ x, int* __restrict__ idx_out) {
    __shared__ __align__(16) float cx[N_], cy[N_], cz[N_];
    __shared__ unsigned kl[4][64], il[4][64];
    int tid = threadIdx.x, blk = blockIdx.x;
    int b = blk >> 7, n0 = (blk & 127) * 16;
    for (int i = tid; i < N_; i += 256) {
        const float* p = x + (size_t)(b * N_ + i) * 3;
        cx[i] = p[0]; cy[i] = p[1]; cz[i] = p[2];
    }
    __syncthreads();
    int w = tid >> 6, lane = tid & 63;
    for (int r = 0; r < 4; ++r) {
        int q = n0 + r * 4 + w;
        float qx = cx[q], qy = cy[q], qz = cz[q];
        unsigned kr[32];
#pragma unroll
        for (int j = 0; j < 8; ++j) {
            float4 vx = *(const float4*)&cx[j * 256 + lane * 4];
            float4 vy = *(const float4*)&cy[j * 256 + lane * 4];
            float4 vz = *(const float4*)&cz[j * 256 + lane * 4];
            float dx, dy, dz;
            dx = qx - vx.x; dy = qy - vy.x; dz = qz - vz.x;
            kr[j * 4 + 0] = fkey(fmaf(dx, dx, fmaf(dy, dy, dz * dz)));
            dx = qx - vx.y; dy = qy - vy.y; dz = qz - vz.y;
            kr[j * 4 + 1] = fkey(fmaf(dx, dx, fmaf(dy, dy, dz * dz)));
            dx = qx - vx.z; dy = qy - vy.z; dz = qz - vz.z;
            kr[j * 4 + 2] = fkey(fmaf(dx, dx, fmaf(dy, dy, dz * dz)));
            dx = qx - vx.w; dy = qy - vy.w; dz = qz - vz.w;
            kr[j * 4 + 3] = fkey(fmaf(dx, dx, fmaf(dy, dy, dz * dz)));
        }
        select20<0>(kr, lane, kl[w], il[w], idx_out + ((size_t)(b * N_ + q)) * KNN);
    }
}

// ---------------- weight prep ----------------
__global__ void wt_kernel(const float* __restrict__ w, const float* __restrict__ b,
                          float* __restrict__ wt, float* __restrict__ bt,
                          int C, int Cout) {
    int N2 = 2 * Cout;
    int t = blockIdx.x * 256 + threadIdx.x;
    if (t < C * N2) {
        int c = t / N2, d = t % N2;
        float v;
        if (d < Cout) v = w[c * Cout + d];
        else          v = w[(C + c) * Cout + (d - Cout)] - w[c * Cout + (d - Cout)];
        wt[t] = v;
    }
    if (t < N2) bt[t] = (t < Cout) ? 0.f : b[t - Cout];
}

__global__ void prep_edge_B(const float* __restrict__ w, const float* __restrict__ b,
                            u16* __restrict__ Bth, u16* __restrict__ Btl,
                            float* __restrict__ bt, int C, int Cout) {
    int N2 = 2 * Cout;
    int t = blockIdx.x * 256 + threadIdx.x;
    if (t < N2 * C) {
        int d = t / C, c = t % C;
        float v = (d < Cout) ? w[c * Cout + d]
                             : (w[(C + c) * Cout + (d - Cout)] - w[c * Cout + (d - Cout)]);
        u16 h = bfhi(v);
        Bth[t] = h; Btl[t] = bflo(v, h);
    }
    if (t < N2) bt[t] = (t < Cout) ? 0.f : b[t - Cout];
}

__global__ void prep_w5_kernel(const float* __restrict__ w5,
                               u16* __restrict__ Bth, u16* __restrict__ Btl) {
    int t = blockIdx.x * 256 + threadIdx.x;   // 1024*512
    int n = t / 512, k = t % 512;
    float v = w5[(size_t)k * 1024 + n];
    u16 h = bfhi(v);
    Bth[t] = h; Btl[t] = bflo(v, h);
}

// ---------------- bf16 MFMA GEMM, 128x128 tile, 4 waves (2x2) ----------------
// Staging: global_load_lds width=16, linear LDS, XOR-swizzled granule.
// EPI 0/1: SPLIT-2 product (aH*bH + aH*bL; A rounded to bf16), XCD-chunked mapping.
// EPI=3: u16 dist keys, HI-ONLY product (1 MFMA), symmetric upper-triangle grid.
template <int EPI>
__launch_bounds__(256, 2)
__global__ void mfma_gemm(const u16* __restrict__ Ah,
                          long long aZ, int lda,
                          const u16* __restrict__ Bh, const u16* __restrict__ Bl,
                          long long bZ, int ldb,
                          const float* __restrict__ ep, long long epZ,
                          float* __restrict__ out, long long outZ, int ldo,
                          int K) {
    __shared__ __align__(16) char smem[73728];
    u16* AsH = (u16*)(smem);
    u16* BsH = (u16*)(smem + 16384);
    u16* BsL = (u16*)(smem + 32768);
    u16 (*LTs)[136] = (u16(*)[136])(smem);   // alias, used post-loop (EPI=3)
    __shared__ float red[2][128];
    int tid = threadIdx.x;
    int m0, n0, mt = 0;
    if (EPI == 3) {
        int t = blockIdx.x, rem = 16, bi = 0;
        while (t >= rem) { t -= rem; ++bi; --rem; }
        m0 = bi * 128; n0 = (bi + t) * 128;
    } else {
        int MT = gridDim.x, NT = gridDim.y;
        int f = blockIdx.x + blockIdx.y * MT;
        int xcd = f & 7, s = f >> 3;
        int sm = s / NT;
        int nt = s - sm * NT;
        mt = xcd * (MT >> 3) + sm;
        m0 = mt * 128; n0 = nt * 128;
    }
    int z = blockIdx.z;
    const u16* ah = Ah + (size_t)z * aZ;
    const u16* bh = Bh + (size_t)z * bZ;
    const u16* bl = Bl + (size_t)z * bZ;
    const float* epz = ep + (size_t)z * epZ;
    float* op = out + (size_t)z * outZ;

    int wid = tid >> 6, lane = tid & 63;
    int wm = wid >> 1, wn = wid & 1;
    int l15 = lane & 15, l4 = lane >> 4;
    int lrow8 = lane >> 3;
    int lg = lane & 7;

    f32x4 acc[4][4];
#pragma unroll
    for (int i = 0; i < 4; ++i)
#pragma unroll
        for (int j = 0; j < 4; ++j) acc[i][j] = (f32x4){0.f, 0.f, 0.f, 0.f};

    for (int k0 = 0; k0 < K; k0 += 64) {
        if (k0) __syncthreads();
#pragma unroll
        for (int ch = 0; ch < 4; ++ch) {
            int row = wid * 32 + ch * 8 + lrow8;
            int gsrc = lg ^ (row & 7);
            unsigned ldsoff = (unsigned)(wid * 32 + ch * 8) * 64;
            size_t ga = (size_t)(m0 + row) * lda + k0 + gsrc * 8;
            size_t gb = (size_t)(n0 + row) * ldb + k0 + gsrc * 8;
            __builtin_amdgcn_global_load_lds((gas_t*)(ah + ga), (las_t*)(AsH + ldsoff), 16, 0, 0);
            __builtin_amdgcn_global_load_lds((gas_t*)(bh + gb), (las_t*)(BsH + ldsoff), 16, 0, 0);
            if (EPI != 3)
                __builtin_amdgcn_global_load_lds((gas_t*)(bl + gb), (las_t*)(BsL + ldsoff), 16, 0, 0);
        }
        __syncthreads();
#pragma unroll
        for (int kk = 0; kk < 2; ++kk) {
            int ko_g = kk * 4 + l4;
            bf16x8 aH[4], bH[4], bL[4];
#pragma unroll
            for (int i = 0; i < 4; ++i) {
                int ra = wm * 64 + i * 16 + l15;
                int oa = ra * 64 + ((ko_g ^ (ra & 7)) << 3);
                aH[i] = *(const bf16x8*)&AsH[oa];
                int rb = wn * 64 + i * 16 + l15;
                int ob = rb * 64 + ((ko_g ^ (rb & 7)) << 3);
                bH[i] = *(const bf16x8*)&BsH[ob];
                if (EPI != 3) bL[i] = *(const bf16x8*)&BsL[ob];
            }
#pragma unroll
            for (int i = 0; i < 4; ++i)
#pragma unroll
                for (int j = 0; j < 4; ++j) {
                    acc[i][j] = __builtin_amdgcn_mfma_f32_16x16x32_bf16(aH[i], bH[j], acc[i][j], 0, 0, 0);
                    if (EPI != 3)
                        acc[i][j] = __builtin_amdgcn_mfma_f32_16x16x32_bf16(aH[i], bL[j], acc[i][j], 0, 0, 0);
                }
        }
    }

    if (EPI == 0) {
#pragma unroll
        for (int i = 0; i < 4; ++i)
#pragma unroll
            for (int r = 0; r < 4; ++r) {
                int grow = m0 + wm * 64 + i * 16 + l4 * 4 + r;
#pragma unroll
                for (int j = 0; j < 4; ++j) {
                    int col = n0 + wn * 64 + j * 16 + l15;
                    op[(size_t)grow * ldo + col] = acc[i][j][r] + epz[col];
                }
            }
    } else if (EPI == 1) {
        float pm[4];
#pragma unroll
        for (int j = 0; j < 4; ++j) {
            float v = -FLT_MAX;
#pragma unroll
            for (int i = 0; i < 4; ++i)
#pragma unroll
                for (int r = 0; r < 4; ++r) v = fmaxf(v, acc[i][j][r]);
            v = fmaxf(v, __shfl_xor(v, 16));
            v = fmaxf(v, __shfl_xor(v, 32));
            pm[j] = v;
        }
        if (l4 == 0) {
#pragma unroll
            for (int j = 0; j < 4; ++j) red[wm][wn * 64 + j * 16 + l15] = pm[j];
        }
        __syncthreads();
        if (tid < 128) {
            float v = fmaxf(red[0][tid], red[1][tid]) + epz[n0 + tid];
            v = (v > 0.f) ? v : 0.2f * v;
            op[(size_t)mt * ldo + n0 + tid] = v;
        }
    } else {
        u16* opu = (u16*)op;
#pragma unroll
        for (int i = 0; i < 4; ++i)
#pragma unroll
            for (int r = 0; r < 4; ++r) {
                int grow = m0 + wm * 64 + i * 16 + l4 * 4 + r;
                float sm = epz[grow];
#pragma unroll
                for (int j = 0; j < 4; ++j) {
                    int col = n0 + wn * 64 + j * 16 + l15;
                    opu[(size_t)grow * ldo + col] = fkey16(sm + epz[col] - 2.f * acc[i][j][r]);
                }
            }
        if (m0 != n0) {
            __syncthreads();   // staging LDS dead; safe to reuse as LTs
#pragma unroll
            for (int i = 0; i < 4; ++i)
#pragma unroll
                for (int j = 0; j < 4; ++j) {
                    int colL  = wn * 64 + j * 16 + l15;
                    int growL = wm * 64 + i * 16 + l4 * 4;
                    unsigned k0v = fkey16(epz[m0 + growL + 0] + epz[n0 + colL] - 2.f * acc[i][j][0]);
                    unsigned k1v = fkey16(epz[m0 + growL + 1] + epz[n0 + colL] - 2.f * acc[i][j][1]);
                    unsigned k2v = fkey16(epz[m0 + growL + 2] + epz[n0 + colL] - 2.f * acc[i][j][2]);
                    unsigned k3v = fkey16(epz[m0 + growL + 3] + epz[n0 + colL] - 2.f * acc[i][j][3]);
                    uint2 pk;
                    pk.x = k0v | (k1v << 16);
                    pk.y = k2v | (k3v << 16);
                    *(uint2*)&LTs[colL][growL] = pk;
                }
            __syncthreads();
            for (int rr0 = 0; rr0 < 128; rr0 += 8) {
                int rr = rr0 + (tid >> 5), cc = (tid & 31) * 4;
                uint2 v = *(const uint2*)&LTs[rr][cc];
                *(uint2*)&opu[(size_t)(n0 + rr) * ldo + m0 + cc] = v;
            }
        }
    }
}

// ---------------- conv1 direct GEMM (K=3) ----------------
__global__ void conv1_kernel(const float* __restrict__ x, const float* __restrict__ wt,
                             const float* __restrict__ bt, float* __restrict__ ut) {
    __shared__ float sw[3][128], sb[128];
    int tid = threadIdx.x;
    if (tid < 128) { sw[0][tid] = wt[tid]; sw[1][tid] = wt[128 + tid]; }
    else { int d = tid - 128; sw[2][d] = wt[256 + d]; sb[d] = bt[d]; }
    __syncthreads();
    int t = blockIdx.x * 256 + tid;
    int m = t >> 7, d = t & 127;
    const float* xm = x + (size_t)m * 3;
    float v = sb[d];
    v = fmaf(xm[0], sw[0][d], v);
    v = fmaf(xm[1], sw[1][d], v);
    v = fmaf(xm[2], sw[2][d], v);
    ut[(size_t)m * 128 + d] = v;
}

// ---------------- gather + leaky + max over k + fused next-conv sqnorm ----------------
template <int COUT>
__global__ void gather_max_kernel(const float* __restrict__ ut,
                                  const int* __restrict__ idx,
                                  u16* __restrict__ cathi, u16* __restrict__ catlo,
                                  int coloff, float* __restrict__ sqn_out) {
    const int P = 256 / COUT;
    int tid = threadIdx.x;
    int p = tid / COUT, d = tid % COUT;
    int nb = gridDim.x;
    int i = blockIdx.x;
    int half = (i >= (nb >> 1)) ? 1 : 0;
    int ii = i - half * (nb >> 1);
    int b = half * 8 + (ii & 7);
    int within = ii >> 3;
    int pt_base = b * 2048 + within * P;
    int pt = pt_base + p;
    int n = pt & 2047;
    __shared__ int sidx[P][KNN];
    __shared__ float wpart[4];
    for (int q = tid; q < P * KNN; q += 256) {
        int pp = q / KNN, kk = q % KNN;
        sidx[pp][kk] = idx[(size_t)(pt_base + pp) * KNN + kk];
    }
    __syncthreads();
    const int N2 = 2 * COUT;
    const float* utb = ut + (size_t)b * N_ * N2;
    float tval = utb[(size_t)n * N2 + COUT + d];
    float acc = -FLT_MAX;
#pragma unroll
    for (int k = 0; k < KNN; k++) {
        int j = __builtin_amdgcn_readfirstlane(sidx[p][k]);
        const float* rp = utb + (size_t)j * N2;
        float s = rp[d] + tval;
        s = (s > 0.f) ? s : 0.2f * s;
        acc = fmaxf(acc, s);
    }
    u16 h = bfhi(acc);
    u16 l = bflo(acc, h);
    cathi[(size_t)pt * 512 + coloff + d] = h;
    catlo[(size_t)pt * 512 + coloff + d] = l;
    if (sqn_out) {
        union { unsigned u; float f; } va, vb;
        va.u = ((unsigned)h) << 16; vb.u = ((unsigned)l) << 16;
        float v = va.f + vb.f;
        float sq = v * v;
#pragma unroll
        for (int off = 1; off < 64; off <<= 1) sq += __shfl_xor(sq, off);
        int wid = tid >> 6, lane = tid & 63;
        if (lane == 0) wpart[wid] = sq;
        __syncthreads();
        const int WPP = COUT / 64;
        if (tid < P) {
            float s2 = 0.f;
#pragma unroll
            for (int ww = 0; ww < WPP; ++ww) s2 += wpart[tid * WPP + ww];
            sqn_out[pt_base + tid] = s2;
        }
    }
}

// ---------------- feat = max over 16 row-blocks of gpart ----------------
__global__ void featmax_kernel(const float* __restrict__ gpart, float* __restrict__ feat) {
    int t = blockIdx.x * 256 + threadIdx.x;   // 16*1024
    int b = t >> 10, d = t & 1023;
    float m = -FLT_MAX;
    for (int rb = 0; rb < 16; ++rb)
        m = fmaxf(m, gpart[(size_t)(b * 16 + rb) * 1024 + d]);
    feat[t] = m;
}

// ---------------- FC k-split: partials over 64-k chunks; W read exactly once ----------------
__global__ void fc_part_kernel(const float* __restrict__ in, const float* __restrict__ W,
                               float* __restrict__ part, int N) {
    __shared__ float sin_[16][64];
    __shared__ float red[3][16][64];
    int tid = threadIdx.x, lane = tid & 63, g = tid >> 6;
    int col = blockIdx.x * 64 + lane;
    int k0 = blockIdx.y * 64;
    for (int i = tid; i < 1024; i += 256)
        sin_[i >> 6][i & 63] = in[(i >> 6) * 1024 + k0 + (i & 63)];
    __syncthreads();
    float acc[16];
#pragma unroll
    for (int b = 0; b < 16; ++b) acc[b] = 0.f;
    int kk0 = g * 16;
#pragma unroll
    for (int k = kk0; k < kk0 + 16; ++k) {
        float wv = W[(size_t)(k0 + k) * N + col];
#pragma unroll
        for (int b = 0; b < 16; ++b) acc[b] = fmaf(sin_[b][k], wv, acc[b]);
    }
    if (g) {
#pragma unroll
        for (int b = 0; b < 16; ++b) red[g - 1][b][lane] = acc[b];
    }
    __syncthreads();
    if (g == 0) {
#pragma unroll
        for (int b = 0; b < 16; ++b) {
            float v = acc[b] + red[0][b][lane] + red[1][b][lane] + red[2][b][lane];
            part[((size_t)blockIdx.y * 16 + b) * N + col] = v;
        }
    }
}

__global__ void fc_reduce_kernel(const float* __restrict__ part, const float* __restrict__ bias,
                                 float* __restrict__ out, int N, int act) {
    int t = blockIdx.x * 256 + threadIdx.x;
    int b = t / N, col = t % N;
    float s = bias[col];
#pragma unroll
    for (int ks = 0; ks < 16; ++ks) s += part[((size_t)ks * 16 + b) * N + col];
    if (act) s = fmaxf(s, 0.f);
    out[(size_t)b * N + col] = s;
}

// ---------------- chamfer pass A ----------------
__launch_bounds__(256)
__global__ void chamferA_kernel(const float* __restrict__ coarse,
                                const float* __restrict__ pts,
                                float* __restrict__ pA) {
    __shared__ float spx[2048], spy[2048], spz[2048];
    __shared__ float red[4];
    int b = blockIdx.x, ch = blockIdx.y, tid = threadIdx.x;
    const float* pb = pts + (size_t)b * 6144;
    for (int i = tid; i < 2048; i += 256) {
        spx[i] = pb[i * 3]; spy[i] = pb[i * 3 + 1]; spz[i] = pb[i * 3 + 2];
    }
    __syncthreads();
    int q = ch * 32 + (tid >> 3);
    int oct = tid & 7;
    const float* cp = coarse + (size_t)b * 3072 + q * 3;
    float cx = cp[0], cy = cp[1], cz = cp[2];
    float mn0 = FLT_MAX, mn1 = FLT_MAX, mn2 = FLT_MAX, mn3 = FLT_MAX;
    int n0 = oct * 256;
    for (int n = n0; n < n0 + 256; n += 4) {
        float dx, dy, dz;
        dx = cx - spx[n];     dy = cy - spy[n];     dz = cz - spz[n];
        mn0 = fminf(mn0, fmaf(dx, dx, fmaf(dy, dy, dz * dz)));
        dx = cx - spx[n + 1]; dy = cy - spy[n + 1]; dz = cz - spz[n + 1];
        mn1 = fminf(mn1, fmaf(dx, dx, fmaf(dy, dy, dz * dz)));
        dx = cx - spx[n + 2]; dy = cy - spy[n + 2]; dz = cz - spz[n + 2];
        mn2 = fminf(mn2, fmaf(dx, dx, fmaf(dy, dy, dz * dz)));
        dx = cx - spx[n + 3]; dy = cy - spy[n + 3]; dz = cz - spz[n + 3];
        mn3 = fminf(mn3, fmaf(dx, dx, fmaf(dy, dy, dz * dz)));
    }
    float mn = fminf(fminf(mn0, mn1), fminf(mn2, mn3));
    mn = fminf(mn, __shfl_xor(mn, 1));
    mn = fminf(mn, __shfl_xor(mn, 2));
    mn = fminf(mn, __shfl_xor(mn, 4));
    float s = (oct == 0) ? mn : 0.f;
#pragma unroll
    for (int off = 32; off > 0; off >>= 1) s += __shfl_down(s, off);
    int w = tid >> 6, lane = tid & 63;
    if (lane == 0) red[w] = s;
    __syncthreads();
    if (tid == 0) pA[b * 32 + ch] = red[0] + red[1] + red[2] + red[3];
}

// ---------------- chamfer pass B ----------------
__launch_bounds__(256)
__global__ void chamferB_kernel(const float* __restrict__ coarse,
                                const float* __restrict__ pts,
                                float* __restrict__ pB) {
    __shared__ float scx[1024], scy[1024], scz[1024];
    __shared__ float red[4];
    int b = blockIdx.x, ch = blockIdx.y, tid = threadIdx.x;
    const float* cb = coarse + (size_t)b * 3072;
    for (int i = tid; i < 1024; i += 256) {
        scx[i] = cb[i * 3]; scy[i] = cb[i * 3 + 1]; scz[i] = cb[i * 3 + 2];
    }
    __syncthreads();
    int p = ch * 64 + (tid >> 2);
    int quad = tid & 3;
    const float* pp = pts + (size_t)b * 6144 + p * 3;
    float px = pp[0], py = pp[1], pz = pp[2];
    float mn0 = FLT_MAX, mn1 = FLT_MAX, mn2 = FLT_MAX, mn3 = FLT_MAX;
    int m0 = quad * 256;
    for (int m = m0; m < m0 + 256; m += 4) {
        float dx, dy, dz;
        dx = px - scx[m];     dy = py - scy[m];     dz = pz - scz[m];
        mn0 = fminf(mn0, fmaf(dx, dx, fmaf(dy, dy, dz * dz)));
        dx = px - scx[m + 1]; dy = py - scy[m + 1]; dz = pz - scz[m + 1];
        mn1 = fminf(mn1, fmaf(dx, dx, fmaf(dy, dy, dz * dz)));
        dx = px - scx[m + 2]; dy = py - scy[m + 2]; dz = pz - scz[m + 2];
        mn2 = fminf(mn2, fmaf(dx, dx, fmaf(dy, dy, dz * dz)));
        dx = px - scx[m + 3]; dy = py - scy[m + 3]; dz = pz - scz[m + 3];
        mn3 = fminf(mn3, fmaf(dx, dx, fmaf(dy, dy, dz * dz)));
    }
    float mn = fminf(fminf(mn0, mn1), fminf(mn2, mn3));
    mn = fminf(mn, __shfl_xor(mn, 1));
    mn = fminf(mn, __shfl_xor(mn, 2));
    float s = (quad == 0) ? mn : 0.f;
#pragma unroll
    for (int off = 32; off > 0; off >>= 1) s += __shfl_down(s, off);
    int w = tid >> 6, lane = tid & 63;
    if (lane == 0) red[w] = s;
    __syncthreads();
    if (tid == 0) pB[b * 32 + ch] = red[0] + red[1] + red[2] + red[3];
}

__global__ void loss_kernel(const float* __restrict__ pA, const float* __restrict__ pB,
                            float* __restrict__ out) {
    __shared__ float rA[4], rB[4];
    int tid = threadIdx.x;   // 256
    float a = pA[tid] + pA[tid + 256];
    float b = pB[tid] + pB[tid + 256];
#pragma unroll
    for (int off = 32; off > 0; off >>= 1) {
        a += __shfl_down(a, off);
        b += __shfl_down(b, off);
    }
    int w = tid >> 6, lane = tid & 63;
    if (lane == 0) { rA[w] = a; rB[w] = b; }
    __syncthreads();
    if (tid == 0)
        out[0] = (rA[0] + rA[1] + rA[2] + rA[3]) / (16.f * 1024.f)
               + (rB[0] + rB[1] + rB[2] + rB[3]) / (16.f * 2048.f);
}

extern "C" void kernel_launch(void* const* d_in, const int* in_sizes, int n_in,
                              void* d_out, int out_size, void* d_ws, size_t ws_size,
                              hipStream_t stream) {
    const float* corrupted = (const float*)d_in[0];
    const float* pts = (const float*)d_in[1];
    const float* w1 = (const float*)d_in[2];   const float* b1 = (const float*)d_in[3];
    const float* w2 = (const float*)d_in[4];   const float* b2 = (const float*)d_in[5];
    const float* w3 = (const float*)d_in[6];   const float* b3 = (const float*)d_in[7];
    const float* w4 = (const float*)d_in[8];   const float* b4 = (const float*)d_in[9];
    const float* w5 = (const float*)d_in[10];  const float* b5 = (const float*)d_in[11];
    const float* fw1 = (const float*)d_in[12]; const float* fb1 = (const float*)d_in[13];
    const float* fw2 = (const float*)d_in[14]; const float* fb2 = (const float*)d_in[15];
    const float* fw3 = (const float*)d_in[16]; const float* fb3 = (const float*)d_in[17];
    float* out = (float*)d_out;

    char* ws = (char*)d_ws;
    u16*   cathi  = (u16*)(ws);                   // [32768][512] bf16 hi   32 MB
    u16*   catlo  = (u16*)(ws + 33554432);        // [32768][512] bf16 lo   32 MB
    float* ut     = (float*)(ws + 67108864);      // [32768][<=512] f32     64 MB (aliased dist/fcpart)
    u16*   dist   = (u16*)ut;                     // [8][2048][2048] u16 keys (64 MB)
    float* fcpart = ut;                           // [16][16][<=3072] f32
    int*   idx    = (int*)  (ws + 134217728);     // [32768][20]
    float* sqn    = (float*)(ws + 136839168);     // [32768]
    u16*   Bth    = (u16*)(ws + 136970240);       // [<=1024][<=512] bf16   1 MB
    u16*   Btl    = (u16*)(ws + 138018816);       // 1 MB
    float* bt     = (float*)(ws + 139067392);     // [<=1024]
    float* gpart  = (float*)(ws + 139071488);     // [256][1024]            1 MB
    float* feat   = (float*)(ws + 140120064);     // [16][1024]
    float* h1     = (float*)(ws + 140185600);
    float* h2     = (float*)(ws + 140251136);
    float* coarse = (float*)(ws + 140316672);     // [16][3072]
    float* pA     = (float*)(ws + 140513280);     // [512]
    float* pB     = (float*)(ws + 140515328);     // [512]
    float* wtf    = (float*)Bth;                  // conv1 fp32 wt alias

    // ---- conv1: C=3 (direct-coord knn, direct K=3 GEMM) ----
    select3_kernel<<<2048, 256, 0, stream>>>(corrupted, idx);
    wt_kernel<<<2, 256, 0, stream>>>(w1, b1, wtf, bt, 3, 64);
    conv1_kernel<<<16384, 256, 0, stream>>>(corrupted, wtf, bt, ut);
    gather_max_kernel<64><<<8192, 256, 0, stream>>>(ut, idx, cathi, catlo, 0, sqn);

    // ---- convs 2-4: symmetric hi-only MFMA gram (u16 keys, 2 groups of z=8) ----
    auto conv = [&](int coloff, int C, int Cout, const float* w, const float* bias, int colout,
                    bool needNextSqn) {
        int N2 = 2 * Cout;
        prep_edge_B<<<(N2 * C + 255) / 256, 256, 0, stream>>>(w, bias, Bth, Btl, bt, C, Cout);
        for (int g = 0; g < 2; ++g) {
            size_t off = ((size_t)g * 8 * N_) * 512 + coloff;
            mfma_gemm<3><<<dim3(136, 1, 8), 256, 0, stream>>>(
                cathi + off, (long long)N_ * 512, 512,
                cathi + off, catlo + off, (long long)N_ * 512, 512,
                sqn + (size_t)g * 8 * N_, N_,
                (float*)dist, (long long)(N_ * N_ / 2), N_, C);   // outZ in f32 units (u16 slice)
            select_kernel<<<4096, 256, 0, stream>>>(dist, idx + (size_t)g * 8 * N_ * KNN);
        }
        mfma_gemm<0><<<dim3(256, N2 / 128, 1), 256, 0, stream>>>(
            cathi + coloff, 0, 512,
            Bth, Btl, 0, C,
            bt, 0,
            ut, 0, N2, C);
        float* sq = needNextSqn ? sqn : nullptr;
        if (Cout == 64)       gather_max_kernel<64><<<8192, 256, 0, stream>>>(ut, idx, cathi, catlo, colout, sq);
        else if (Cout == 128) gather_max_kernel<128><<<16384, 256, 0, stream>>>(ut, idx, cathi, catlo, colout, sq);
        else                  gather_max_kernel<256><<<32768, 256, 0, stream>>>(ut, idx, cathi, catlo, colout, sq);
    };
    conv(0, 64, 64, w2, b2, 64, true);
    conv(64, 64, 128, w3, b3, 128, true);
    conv(128, 128, 256, w4, b4, 256, false);

    // ---- w5 + leaky + max over N (fused epilogue, split-2) ----
    prep_w5_kernel<<<2048, 256, 0, stream>>>(w5, Bth, Btl);
    mfma_gemm<1><<<dim3(256, 8, 1), 256, 0, stream>>>(
        cathi, 0, 512,
        Bth, Btl, 0, 512,
        b5, 0,
        gpart, 0, 1024, 512);
    featmax_kernel<<<64, 256, 0, stream>>>(gpart, feat);

    // ---- FCs: k-split partials + reduce (deterministic) ----
    fc_part_kernel<<<dim3(16, 16), 256, 0, stream>>>(feat, fw1, fcpart, 1024);
    fc_reduce_kernel<<<64, 256, 0, stream>>>(fcpart, fb1, h1, 1024, 1);
    fc_part_kernel<<<dim3(16, 16), 256, 0, stream>>>(h1, fw2, fcpart, 1024);
    fc_reduce_kernel<<<64, 256, 0, stream>>>(fcpart, fb2, h2, 1024, 1);
    fc_part_kernel<<<dim3(48, 16), 256, 0, stream>>>(h2, fw3, fcpart, 3072);
    fc_reduce_kernel<<<192, 256, 0, stream>>>(fcpart, fb3, coarse, 3072, 0);

    chamferA_kernel<<<dim3(16, 32), 256, 0, stream>>>(coarse, pts, pA);
    chamferB_kernel<<<dim3(16, 32), 256, 0, stream>>>(coarse, pts, pB);
    loss_kernel<<<1, 256, 0, stream>>>(pA, pB, out);
}